// Round 8
// baseline (226.124 us; speedup 1.0000x reference)
//
#include <hip/hip_runtime.h>
#include <hip/hip_bf16.h>
#include <hip/hip_fp16.h>
#include <cstdint>

static constexpr int NB  = 8;
static constexpr int HH  = 96;
static constexpr int WW  = 96;
static constexpr int NP  = 9216;   // 96*96
static constexpr int NPK = 576;    // 24*24

using bf8 = __attribute__((ext_vector_type(8))) short;
using f4  = __attribute__((ext_vector_type(4))) float;

__device__ __forceinline__ unsigned pack_bf2(float a, float b) {
    __hip_bfloat162 h = __float22bfloat162_rn(make_float2(a, b));
    unsigned u; __builtin_memcpy(&u, &h, 4);
    return u;
}

// ---------------------------------------------------------------------------
// MFMA conv1x1, 4-pixel-per-lane vectorized.  (unchanged from round 7)
// ---------------------------------------------------------------------------
template<int C, int OT, int MIN, int MOUT>
__global__ __launch_bounds__(256) void k_mfma_conv(
    const float* __restrict__ in0, const float* __restrict__ in1,
    const float* __restrict__ w, const float* __restrict__ bias,
    float* __restrict__ out, int np, long long ibs, long long i1bs,
    int storeO, int QITER)
{
    constexpr int KT = C / 32;
    const int tid  = threadIdx.x;
    const int lane = tid & 63, wid = tid >> 6;
    const int b    = blockIdx.z;
    const int obq  = blockIdx.y * (OT * 16);
    const int arow = lane & 15, agrp = lane >> 4;
    const int nquad = np >> 6;

    bf8 afr[OT][KT];
#pragma unroll
    for (int ot = 0; ot < OT; ++ot)
#pragma unroll
        for (int kt = 0; kt < KT; ++kt) {
            const float* wp = w + (long long)(obq + ot * 16 + arow) * C + kt * 32 + agrp * 8;
            int4 t;
            t.x = (int)pack_bf2(wp[0], wp[1]);
            t.y = (int)pack_bf2(wp[2], wp[3]);
            t.z = (int)pack_bf2(wp[4], wp[5]);
            t.w = (int)pack_bf2(wp[6], wp[7]);
            afr[ot][kt] = __builtin_bit_cast(bf8, t);
        }

    const float* x0 = in0 + (long long)b * ibs;
    const float* x1 = in1 ? (in1 + (long long)b * i1bs) : nullptr;

    for (int it = 0; it < QITER; ++it) {
        const int quad = blockIdx.x * (4 * QITER) + it * 4 + wid;
        if (quad >= nquad) continue;
        const int p0 = quad * 64 + arow * 4;

        f4 acc[4][OT];
#pragma unroll
        for (int i = 0; i < 4; ++i)
#pragma unroll
            for (int ot = 0; ot < OT; ++ot) acc[i][ot] = (f4){0.f, 0.f, 0.f, 0.f};

#pragma unroll
        for (int kt = 0; kt < KT; ++kt) {
            const long long cbase = kt * 32 + agrp * 8;
            int uu[4][4];
#pragma unroll
            for (int jj = 0; jj < 4; ++jj) {
                float4 a0 = *(const float4*)&x0[(cbase + 2 * jj) * np + p0];
                float4 a1 = *(const float4*)&x0[(cbase + 2 * jj + 1) * np + p0];
                if (MIN == 1) {
                    float4 y0 = *(const float4*)&x1[(cbase + 2 * jj) * np + p0];
                    float4 y1 = *(const float4*)&x1[(cbase + 2 * jj + 1) * np + p0];
                    a0.x *= y0.x; a0.y *= y0.y; a0.z *= y0.z; a0.w *= y0.w;
                    a1.x *= y1.x; a1.y *= y1.y; a1.z *= y1.z; a1.w *= y1.w;
                }
                uu[0][jj] = (int)pack_bf2(a0.x, a1.x);
                uu[1][jj] = (int)pack_bf2(a0.y, a1.y);
                uu[2][jj] = (int)pack_bf2(a0.z, a1.z);
                uu[3][jj] = (int)pack_bf2(a0.w, a1.w);
            }
#pragma unroll
            for (int i = 0; i < 4; ++i) {
                int4 ti = {uu[i][0], uu[i][1], uu[i][2], uu[i][3]};
                bf8 bfr = __builtin_bit_cast(bf8, ti);
#pragma unroll
                for (int ot = 0; ot < OT; ++ot)
                    acc[i][ot] = __builtin_amdgcn_mfma_f32_16x16x32_bf16(afr[ot][kt], bfr, acc[i][ot], 0, 0, 0);
            }
        }

#pragma unroll
        for (int ot = 0; ot < OT; ++ot) {
#pragma unroll
            for (int r = 0; r < 4; ++r) {
                const int o = obq + ot * 16 + agrp * 4 + r;
                const float bs = bias[o];
                float4 v;
                v.x = acc[0][ot][r] + bs;
                v.y = acc[1][ot][r] + bs;
                v.z = acc[2][ot][r] + bs;
                v.w = acc[3][ot][r] + bs;
                if (MOUT == 1) {
                    v.x = v.x / (1.f + __expf(-v.x));
                    v.y = v.y / (1.f + __expf(-v.y));
                    v.z = v.z / (1.f + __expf(-v.z));
                    v.w = v.w / (1.f + __expf(-v.w));
                } else if (MOUT == 2) {
                    float4 vx = *(const float4*)&x1[(long long)o * np + p0];
                    v.x = tanhf(v.x * 0.25f) * vx.x;
                    v.y = tanhf(v.y * 0.25f) * vx.y;
                    v.z = tanhf(v.z * 0.25f) * vx.z;
                    v.w = tanhf(v.w * 0.25f) * vx.w;
                }
                *(float4*)&out[((long long)b * storeO + o) * np + p0] = v;
            }
        }
    }
}

// ---------------------------------------------------------------------------
// depthwise 5x5, pad 2 — LDS-staged.  (unchanged)
// ---------------------------------------------------------------------------
__global__ __launch_bounds__(256) void k_dwconv5_lds(
    const float* __restrict__ in, const float* __restrict__ w,
    const float* __restrict__ bias, float* __restrict__ out, int ch_total)
{
    __shared__ __align__(16) float img[NP];
    const int tid = threadIdx.x;
    const int ch  = blockIdx.x;
    const int b   = blockIdx.y;
    const float* ip = in + ((long long)b * ch_total + ch) * NP;

#pragma unroll
    for (int j = 0; j < 9; ++j)
        ((float4*)img)[tid + 256 * j] = ((const float4*)ip)[tid + 256 * j];
    __syncthreads();

    const float* wp = w + ch * 25;
    float wr[25];
#pragma unroll
    for (int i = 0; i < 25; ++i) wr[i] = wp[i];
    const float bs = bias[ch];

    float* op = out + ((long long)b * ch_total + ch) * NP;

#pragma unroll
    for (int j = 0; j < 9; ++j) {
        const int q  = tid + 256 * j;
        const int y  = q / 24;
        const int x4 = (q - y * 24) * 4;
        float o0 = bs, o1 = bs, o2 = bs, o3 = bs;
#pragma unroll
        for (int ky = 0; ky < 5; ++ky) {
            const int yy = y + ky - 2;
            if (yy < 0 || yy >= HH) continue;
            const float* row = &img[yy * WW + x4];
            float4 mid = *(const float4*)row;
            float4 lf  = (x4 >= 4)      ? *(const float4*)(row - 4)
                                        : make_float4(0.f, 0.f, 0.f, 0.f);
            float4 rt  = (x4 + 4 < WW)  ? *(const float4*)(row + 4)
                                        : make_float4(0.f, 0.f, 0.f, 0.f);
            const float f0 = lf.z,  f1 = lf.w;
            const float f2 = mid.x, f3 = mid.y, f4v = mid.z, f5 = mid.w;
            const float f6 = rt.x,  f7 = rt.y;
            const float w0 = wr[ky * 5 + 0], w1 = wr[ky * 5 + 1],
                        w2 = wr[ky * 5 + 2], w3 = wr[ky * 5 + 3],
                        w4 = wr[ky * 5 + 4];
            o0 = fmaf(w0, f0, o0); o0 = fmaf(w1, f1, o0); o0 = fmaf(w2, f2, o0);
            o0 = fmaf(w3, f3, o0); o0 = fmaf(w4, f4v, o0);
            o1 = fmaf(w0, f1, o1); o1 = fmaf(w1, f2, o1); o1 = fmaf(w2, f3, o1);
            o1 = fmaf(w3, f4v, o1); o1 = fmaf(w4, f5, o1);
            o2 = fmaf(w0, f2, o2); o2 = fmaf(w1, f3, o2); o2 = fmaf(w2, f4v, o2);
            o2 = fmaf(w3, f5, o2); o2 = fmaf(w4, f6, o2);
            o3 = fmaf(w0, f3, o3); o3 = fmaf(w1, f4v, o3); o3 = fmaf(w2, f5, o3);
            o3 = fmaf(w3, f6, o3); o3 = fmaf(w4, f7, o3);
        }
        *(float4*)&op[y * WW + x4] = make_float4(o0, o1, o2, o3);
    }
}

// ---------------------------------------------------------------------------
// 4x4 average pool  (unchanged)
// ---------------------------------------------------------------------------
__global__ __launch_bounds__(256) void k_avgpool4(
    const float* __restrict__ in, float* __restrict__ out)
{
    int idx = blockIdx.x * 256 + threadIdx.x;
    int total = NB * 128 * NPK;
    if (idx >= total) return;
    int pw = idx % 24;
    int t  = idx / 24;
    int ph = t % 24;  t /= 24;
    int c  = t % 128;
    int b  = t / 128;
    const float* ip = in + ((long long)b * 128 + c) * NP + (ph * 4) * WW + pw * 4;
    float s = 0.f;
#pragma unroll
    for (int i = 0; i < 4; ++i)
#pragma unroll
        for (int j = 0; j < 4; ++j) s += ip[i * WW + j];
    out[idx] = s * (1.0f / 16.0f);
}

// ---------------------------------------------------------------------------
// MFMA flash-attention v2.
// Changes vs r7 (which passed at 61 µs, latency-bound @ 12 waves/CU):
//  - 8-wave blocks (512 thr): staging halved, more waves/CU.
//  - E relayout buffer s-serialized: 128 uint2 per wave (4KB total/8 waves).
//  - den accumulated by MFMA with A=ones (reuses PV B-frag; no VALU adds,
//    no final shfl; den bf16-consistent with numerator).
//  - exp2: Q pre-scaled by 0.25*log2(e); exp2f == v_exp_f32 (no mul).
// LDS: K 18KB + z 0.5KB + V^T 18KB + E 8KB = 44.5KB.
// Grid: (36, 32); block covers 256 q of one (b,h).
// ---------------------------------------------------------------------------
__global__ __launch_bounds__(512) void k_attn_mfma(
    const float* __restrict__ q,    // (B,64,NP)
    const float* __restrict__ kv,   // (B,128,NPK): k ch 0..63, v ch 64..127
    float* __restrict__ hilo)       // (B,128,NP), lo at ch 64..127
{
    __shared__ __align__(16) int4  klds4[36 * 32];   // [tile16][slot]  18KB
    __shared__ __align__(16) int4  zlds4[32];        // zero block      0.5KB
    __shared__ __align__(16) int4  vlds4[18 * 64];   // [tile32][lane]  18KB
    __shared__ __align__(16) uint2 elds2[8 * 128];   // per-wave E buf  8KB

    const int tid  = threadIdx.x;
    const int lane = tid & 63, wid = tid >> 6;
    const int g    = lane >> 4, qi = lane & 15;
    const int bh   = blockIdx.y, b = bh >> 2, h = bh & 3;

    const float* kbase = kv + ((long long)b * 128 + h * 16) * NPK;
    const float* vbase = kv + ((long long)b * 128 + 64 + h * 16) * NPK;

    // ---- stage K as QK A-frags
    for (int i = tid; i < 1152; i += 512) {
        const int key = i >> 1, dg = i & 1;
        const float* kp = kbase + (long long)(dg * 8) * NPK + key;
        int4 t;
        t.x = (int)pack_bf2(kp[0],       kp[NPK]);
        t.y = (int)pack_bf2(kp[2 * NPK], kp[3 * NPK]);
        t.z = (int)pack_bf2(kp[4 * NPK], kp[5 * NPK]);
        t.w = (int)pack_bf2(kp[6 * NPK], kp[7 * NPK]);
        klds4[(key >> 4) * 32 + dg * 16 + (key & 15)] = t;
    }
    // ---- stage V^T as PV A-frags
    for (int i = tid; i < 1152; i += 512) {
        const int t = i >> 6, l = i & 63;
        const float* vp = vbase + (long long)(l & 15) * NPK + t * 32 + (l >> 4) * 8;
        float4 a = *(const float4*)vp;
        float4 c = *(const float4*)(vp + 4);
        int4 tt;
        tt.x = (int)pack_bf2(a.x, a.y);
        tt.y = (int)pack_bf2(a.z, a.w);
        tt.z = (int)pack_bf2(c.x, c.y);
        tt.w = (int)pack_bf2(c.z, c.w);
        vlds4[i] = tt;
    }
    if (tid < 32) zlds4[tid] = make_int4(0, 0, 0, 0);
    __syncthreads();

    // ---- Q B-frags for 2 q-subtiles; scale folds SCALOR * log2(e)
    const float qs = 0.25f * 1.4426950408889634f;
    const int q0 = (blockIdx.x * 8 + wid) * 32;
    const float* qcol = q + ((long long)b * 64 + h * 16) * NP + q0 + qi;
    int4 qv[2] = { make_int4(0, 0, 0, 0), make_int4(0, 0, 0, 0) };
    if (g < 2) {
#pragma unroll
        for (int s = 0; s < 2; ++s) {
            const float* qp = qcol + s * 16 + (long long)(g * 8) * NP;
            qv[s].x = (int)pack_bf2(qp[0]        * qs, qp[(long long)NP] * qs);
            qv[s].y = (int)pack_bf2(qp[2ll * NP] * qs, qp[3ll * NP]      * qs);
            qv[s].z = (int)pack_bf2(qp[4ll * NP] * qs, qp[5ll * NP]      * qs);
            qv[s].w = (int)pack_bf2(qp[6ll * NP] * qs, qp[7ll * NP]      * qs);
        }
    }

    const bf8 ones = { (short)0x3F80, (short)0x3F80, (short)0x3F80, (short)0x3F80,
                       (short)0x3F80, (short)0x3F80, (short)0x3F80, (short)0x3F80 };

    f4 accp[2] = { (f4){0.f, 0.f, 0.f, 0.f}, (f4){0.f, 0.f, 0.f, 0.f} };
    f4 dacc[2] = { (f4){0.f, 0.f, 0.f, 0.f}, (f4){0.f, 0.f, 0.f, 0.f} };
    const int wb = wid * 128;

    for (int k2 = 0; k2 < 18; ++k2) {
        const int4 kf0 = (lane < 32) ? klds4[(k2 * 2 + 0) * 32 + lane] : zlds4[lane & 31];
        const int4 kf1 = (lane < 32) ? klds4[(k2 * 2 + 1) * 32 + lane] : zlds4[lane & 31];
        const bf8 ka0 = __builtin_bit_cast(bf8, kf0);
        const bf8 ka1 = __builtin_bit_cast(bf8, kf1);
        const bf8 va  = __builtin_bit_cast(bf8, vlds4[k2 * 64 + lane]);
#pragma unroll
        for (int s = 0; s < 2; ++s) {
            f4 sa0 = __builtin_amdgcn_mfma_f32_16x16x32_bf16(
                ka0, __builtin_bit_cast(bf8, qv[s]), (f4){0.f, 0.f, 0.f, 0.f}, 0, 0, 0);
            f4 sa1 = __builtin_amdgcn_mfma_f32_16x16x32_bf16(
                ka1, __builtin_bit_cast(bf8, qv[s]), (f4){0.f, 0.f, 0.f, 0.f}, 0, 0, 0);
            elds2[wb + g * 16 + qi] =
                make_uint2(pack_bf2(exp2f(sa0[0]), exp2f(sa0[1])),
                           pack_bf2(exp2f(sa0[2]), exp2f(sa0[3])));
            elds2[wb + 64 + g * 16 + qi] =
                make_uint2(pack_bf2(exp2f(sa1[0]), exp2f(sa1[1])),
                           pack_bf2(exp2f(sa1[2]), exp2f(sa1[3])));
            const int rbase = wb + (g >> 1) * 64 + (g & 1) * 32 + qi;
            const uint2 r0 = elds2[rbase];
            const uint2 r1 = elds2[rbase + 16];
            int4 ti = make_int4((int)r0.x, (int)r0.y, (int)r1.x, (int)r1.y);
            accp[s] = __builtin_amdgcn_mfma_f32_16x16x32_bf16(
                va, __builtin_bit_cast(bf8, ti), accp[s], 0, 0, 0);
            dacc[s] = __builtin_amdgcn_mfma_f32_16x16x32_bf16(
                ones, __builtin_bit_cast(bf8, ti), dacc[s], 0, 0, 0);
        }
    }

#pragma unroll
    for (int s = 0; s < 2; ++s) {
        const float inv = 1.0f / dacc[s][0];
        float* op = hilo + ((long long)b * 128 + 64 + h * 16 + g * 4) * NP + q0 + s * 16 + qi;
#pragma unroll
        for (int r = 0; r < 4; ++r)
            op[(long long)r * NP] = accp[s][r] * inv;
    }
}

// ---------------------------------------------------------------------------
extern "C" void kernel_launch(void* const* d_in, const int* in_sizes, int n_in,
                              void* d_out, int out_size, void* d_ws, size_t ws_size,
                              hipStream_t stream)
{
    const float* x      = (const float*)d_in[0];
    const float* qkv_w  = (const float*)d_in[1];
    const float* qkv_b  = (const float*)d_in[2];
    const float* dw_w   = (const float*)d_in[3];
    const float* dw_b   = (const float*)d_in[4];
    const float* am_w1  = (const float*)d_in[5];
    const float* am_b1  = (const float*)d_in[6];
    const float* am_w2  = (const float*)d_in[7];
    const float* am_b2  = (const float*)d_in[8];
    const float* gq_w   = (const float*)d_in[9];
    const float* gq_b   = (const float*)d_in[10];
    const float* gkv_w  = (const float*)d_in[11];
    const float* gkv_b  = (const float*)d_in[12];
    const float* proj_w = (const float*)d_in[13];
    const float* proj_b = (const float*)d_in[14];
    float* out = (float*)d_out;
    float* ws  = (float*)d_ws;

    float* t_qkv  = ws;                     // (8,192,9216)
    float* t_hilo = ws;                     // (8,128,9216): hi ch 0..63, lo 64..127
    float* t_a    = ws + 9437184;           // (8,64,9216)
    float* t_dw   = ws + 14155776;          // (8,192,9216)
    float* t_gq   = ws + 28311552;          // (8,64,9216)
    float* t_pool = ws + 33030144;          // (8,128,576)
    float* t_gkv  = ws + 33619968;          // (8,128,576)

    const long long ibs_x  = (long long)128 * NP;
    const long long ibs_dw = (long long)192 * NP;

    // 1. qkv = conv1x1(x)                        (8,192,96,96)
    k_mfma_conv<128,4,0,0><<<dim3(36,3,NB), 256, 0, stream>>>(
        x, nullptr, qkv_w, qkv_b, t_qkv, NP, ibs_x, 0, 192, 1);
    // 2. depthwise 5x5 (LDS-staged)
    k_dwconv5_lds<<<dim3(192, NB), 256, 0, stream>>>(t_qkv, dw_w, dw_b, t_dw, 192);
    // 3. gq = conv1x1(x)                         (8,64,96,96)
    k_mfma_conv<128,4,0,0><<<dim3(36,1,NB), 256, 0, stream>>>(
        x, nullptr, gq_w, gq_b, t_gq, NP, ibs_x, 0, 64, 1);
    // 4. pooled = avgpool4(x)                    (8,128,24,24)
    k_avgpool4<<<dim3((NB*128*NPK + 255)/256), 256, 0, stream>>>(x, t_pool);
    // 5. gkv = conv1x1(pooled)                   (8,128,24,24)
    k_mfma_conv<128,4,0,0><<<dim3(3,2,NB), 256, 0, stream>>>(
        t_pool, nullptr, gkv_w, gkv_b, t_gkv, NPK, (long long)128 * NPK, 0, 128, 1);
    // 6. a = silu(conv1x1(q*k))                  q=dw[0:64], k=dw[64:128]
    k_mfma_conv<64,4,1,1><<<dim3(36,1,NB), 256, 0, stream>>>(
        t_dw, t_dw + (long long)64 * NP, am_w1, am_b1, t_a, NP, ibs_dw, ibs_dw, 64, 1);
    // 7. hi = tanh(conv1x1(a)*0.25) * v          v=dw[128:192] -> hilo ch 0..63
    k_mfma_conv<64,4,0,2><<<dim3(36,1,NB), 256, 0, stream>>>(
        t_a, t_dw + (long long)128 * NP, am_w2, am_b2, t_hilo, NP,
        (long long)64 * NP, ibs_dw, 128, 1);
    // 8. lo = MFMA flash attention(gq, gkv)      -> hilo ch 64..127
    k_attn_mfma<<<dim3(36, 32), 512, 0, stream>>>(t_gq, t_gkv, t_hilo);
    // 9. out = conv1x1(hilo, proj_w)
    k_mfma_conv<128,4,0,0><<<dim3(36,2,NB), 256, 0, stream>>>(
        t_hilo, nullptr, proj_w, proj_b, out, NP, ibs_x, 0, 128, 1);
}

// Round 10
// 219.540 us; speedup vs baseline: 1.0300x; 1.0300x over previous
//
#include <hip/hip_runtime.h>
#include <hip/hip_bf16.h>
#include <hip/hip_fp16.h>
#include <cstdint>

static constexpr int NB  = 8;
static constexpr int HH  = 96;
static constexpr int WW  = 96;
static constexpr int NP  = 9216;   // 96*96
static constexpr int NPK = 576;    // 24*24

using bf8 = __attribute__((ext_vector_type(8))) short;
using f4  = __attribute__((ext_vector_type(4))) float;

__device__ __forceinline__ unsigned pack_bf2(float a, float b) {
    __hip_bfloat162 h = __float22bfloat162_rn(make_float2(a, b));
    unsigned u; __builtin_memcpy(&u, &h, 4);
    return u;
}

// ---------------------------------------------------------------------------
// MFMA conv1x1, 4-pixel-per-lane vectorized.  (verified since round 5)
// ---------------------------------------------------------------------------
template<int C, int OT, int MIN, int MOUT>
__global__ __launch_bounds__(256) void k_mfma_conv(
    const float* __restrict__ in0, const float* __restrict__ in1,
    const float* __restrict__ w, const float* __restrict__ bias,
    float* __restrict__ out, int np, long long ibs, long long i1bs,
    int storeO, int QITER)
{
    constexpr int KT = C / 32;
    const int tid  = threadIdx.x;
    const int lane = tid & 63, wid = tid >> 6;
    const int b    = blockIdx.z;
    const int obq  = blockIdx.y * (OT * 16);
    const int arow = lane & 15, agrp = lane >> 4;
    const int nquad = np >> 6;

    bf8 afr[OT][KT];
#pragma unroll
    for (int ot = 0; ot < OT; ++ot)
#pragma unroll
        for (int kt = 0; kt < KT; ++kt) {
            const float* wp = w + (long long)(obq + ot * 16 + arow) * C + kt * 32 + agrp * 8;
            int4 t;
            t.x = (int)pack_bf2(wp[0], wp[1]);
            t.y = (int)pack_bf2(wp[2], wp[3]);
            t.z = (int)pack_bf2(wp[4], wp[5]);
            t.w = (int)pack_bf2(wp[6], wp[7]);
            afr[ot][kt] = __builtin_bit_cast(bf8, t);
        }

    const float* x0 = in0 + (long long)b * ibs;
    const float* x1 = in1 ? (in1 + (long long)b * i1bs) : nullptr;

    for (int it = 0; it < QITER; ++it) {
        const int quad = blockIdx.x * (4 * QITER) + it * 4 + wid;
        if (quad >= nquad) continue;
        const int p0 = quad * 64 + arow * 4;

        f4 acc[4][OT];
#pragma unroll
        for (int i = 0; i < 4; ++i)
#pragma unroll
            for (int ot = 0; ot < OT; ++ot) acc[i][ot] = (f4){0.f, 0.f, 0.f, 0.f};

#pragma unroll
        for (int kt = 0; kt < KT; ++kt) {
            const long long cbase = kt * 32 + agrp * 8;
            int uu[4][4];
#pragma unroll
            for (int jj = 0; jj < 4; ++jj) {
                float4 a0 = *(const float4*)&x0[(cbase + 2 * jj) * np + p0];
                float4 a1 = *(const float4*)&x0[(cbase + 2 * jj + 1) * np + p0];
                if (MIN == 1) {
                    float4 y0 = *(const float4*)&x1[(cbase + 2 * jj) * np + p0];
                    float4 y1 = *(const float4*)&x1[(cbase + 2 * jj + 1) * np + p0];
                    a0.x *= y0.x; a0.y *= y0.y; a0.z *= y0.z; a0.w *= y0.w;
                    a1.x *= y1.x; a1.y *= y1.y; a1.z *= y1.z; a1.w *= y1.w;
                }
                uu[0][jj] = (int)pack_bf2(a0.x, a1.x);
                uu[1][jj] = (int)pack_bf2(a0.y, a1.y);
                uu[2][jj] = (int)pack_bf2(a0.z, a1.z);
                uu[3][jj] = (int)pack_bf2(a0.w, a1.w);
            }
#pragma unroll
            for (int i = 0; i < 4; ++i) {
                int4 ti = {uu[i][0], uu[i][1], uu[i][2], uu[i][3]};
                bf8 bfr = __builtin_bit_cast(bf8, ti);
#pragma unroll
                for (int ot = 0; ot < OT; ++ot)
                    acc[i][ot] = __builtin_amdgcn_mfma_f32_16x16x32_bf16(afr[ot][kt], bfr, acc[i][ot], 0, 0, 0);
            }
        }

#pragma unroll
        for (int ot = 0; ot < OT; ++ot) {
#pragma unroll
            for (int r = 0; r < 4; ++r) {
                const int o = obq + ot * 16 + agrp * 4 + r;
                const float bs = bias[o];
                float4 v;
                v.x = acc[0][ot][r] + bs;
                v.y = acc[1][ot][r] + bs;
                v.z = acc[2][ot][r] + bs;
                v.w = acc[3][ot][r] + bs;
                if (MOUT == 1) {
                    v.x = v.x / (1.f + __expf(-v.x));
                    v.y = v.y / (1.f + __expf(-v.y));
                    v.z = v.z / (1.f + __expf(-v.z));
                    v.w = v.w / (1.f + __expf(-v.w));
                } else if (MOUT == 2) {
                    float4 vx = *(const float4*)&x1[(long long)o * np + p0];
                    v.x = tanhf(v.x * 0.25f) * vx.x;
                    v.y = tanhf(v.y * 0.25f) * vx.y;
                    v.z = tanhf(v.z * 0.25f) * vx.z;
                    v.w = tanhf(v.w * 0.25f) * vx.w;
                }
                *(float4*)&out[((long long)b * storeO + o) * np + p0] = v;
            }
        }
    }
}

// ---------------------------------------------------------------------------
// Fused am1+am2: a = silu(W1·(q∘k)+b1); hi = tanh((W2·a+b2)·0.25)·v.
// One wave owns a 64-px quad and ALL 64 channels of `a` — the a->B-frag
// relayout is a per-wave LDS round-trip (XOR-swizzled, no barrier).
// Identical rounding path to the unfused pair (a passed through pack_bf2).
// ---------------------------------------------------------------------------
__global__ __launch_bounds__(256) void k_am_fused(
    const float* __restrict__ dw,    // t_dw: q +0, k +64NP, v +128NP (bstride 192NP)
    const float* __restrict__ w1, const float* __restrict__ b1v,
    const float* __restrict__ w2, const float* __restrict__ b2v,
    float* __restrict__ hi)          // t_hilo ch 0..63 (bstride 128NP)
{
    __shared__ __align__(16) uint2 abuf[4][1024];   // [wave][px*16 + (c2^arow)] 32KB

    const int tid  = threadIdx.x;
    const int lane = tid & 63, wid = tid >> 6;
    const int b    = blockIdx.z;
    const int arow = lane & 15, agrp = lane >> 4;

    bf8 afr1[4][2], afr2[4][2];
#pragma unroll
    for (int ot = 0; ot < 4; ++ot)
#pragma unroll
        for (int kt = 0; kt < 2; ++kt) {
            const float* wp1 = w1 + (long long)(ot * 16 + arow) * 64 + kt * 32 + agrp * 8;
            const float* wp2 = w2 + (long long)(ot * 16 + arow) * 64 + kt * 32 + agrp * 8;
            int4 t1, t2;
            t1.x = (int)pack_bf2(wp1[0], wp1[1]);  t2.x = (int)pack_bf2(wp2[0], wp2[1]);
            t1.y = (int)pack_bf2(wp1[2], wp1[3]);  t2.y = (int)pack_bf2(wp2[2], wp2[3]);
            t1.z = (int)pack_bf2(wp1[4], wp1[5]);  t2.z = (int)pack_bf2(wp2[4], wp2[5]);
            t1.w = (int)pack_bf2(wp1[6], wp1[7]);  t2.w = (int)pack_bf2(wp2[6], wp2[7]);
            afr1[ot][kt] = __builtin_bit_cast(bf8, t1);
            afr2[ot][kt] = __builtin_bit_cast(bf8, t2);
        }

    const float* xq = dw + (long long)b * (192ll * NP);
    const float* xk = xq + 64ll * NP;
    const float* xv = xq + 128ll * NP;

    const int quad = blockIdx.x * 4 + wid;          // 36*4 = 144 quads
    const int p0 = quad * 64 + arow * 4;

    // ---- stage 1: acc1 = W1 · (q*k)
    f4 acc1[4][4];
#pragma unroll
    for (int i = 0; i < 4; ++i)
#pragma unroll
        for (int ot = 0; ot < 4; ++ot) acc1[i][ot] = (f4){0.f, 0.f, 0.f, 0.f};

#pragma unroll
    for (int kt = 0; kt < 2; ++kt) {
        const long long cbase = kt * 32 + agrp * 8;
        int uu[4][4];
#pragma unroll
        for (int jj = 0; jj < 4; ++jj) {
            float4 a0 = *(const float4*)&xq[(cbase + 2 * jj) * NP + p0];
            float4 a1 = *(const float4*)&xq[(cbase + 2 * jj + 1) * NP + p0];
            float4 y0 = *(const float4*)&xk[(cbase + 2 * jj) * NP + p0];
            float4 y1 = *(const float4*)&xk[(cbase + 2 * jj + 1) * NP + p0];
            a0.x *= y0.x; a0.y *= y0.y; a0.z *= y0.z; a0.w *= y0.w;
            a1.x *= y1.x; a1.y *= y1.y; a1.z *= y1.z; a1.w *= y1.w;
            uu[0][jj] = (int)pack_bf2(a0.x, a1.x);
            uu[1][jj] = (int)pack_bf2(a0.y, a1.y);
            uu[2][jj] = (int)pack_bf2(a0.z, a1.z);
            uu[3][jj] = (int)pack_bf2(a0.w, a1.w);
        }
#pragma unroll
        for (int i = 0; i < 4; ++i) {
            int4 ti = {uu[i][0], uu[i][1], uu[i][2], uu[i][3]};
            bf8 bfr = __builtin_bit_cast(bf8, ti);
#pragma unroll
            for (int ot = 0; ot < 4; ++ot)
                acc1[i][ot] = __builtin_amdgcn_mfma_f32_16x16x32_bf16(afr1[ot][kt], bfr, acc1[i][ot], 0, 0, 0);
        }
    }

    // ---- silu + bf16 pack into per-wave LDS (ch-pair layout, XOR swizzle)
#pragma unroll
    for (int i = 0; i < 4; ++i)
#pragma unroll
        for (int ot = 0; ot < 4; ++ot) {
            const int ch0 = ot * 16 + agrp * 4;
            float v0 = acc1[i][ot][0] + b1v[ch0 + 0];
            float v1 = acc1[i][ot][1] + b1v[ch0 + 1];
            float v2 = acc1[i][ot][2] + b1v[ch0 + 2];
            float v3 = acc1[i][ot][3] + b1v[ch0 + 3];
            v0 = v0 / (1.f + __expf(-v0));
            v1 = v1 / (1.f + __expf(-v1));
            v2 = v2 / (1.f + __expf(-v2));
            v3 = v3 / (1.f + __expf(-v3));
            const int c2 = ot * 4 + agrp;            // uint2 index (4 ch)
            abuf[wid][(arow * 4 + i) * 16 + (c2 ^ arow)] =
                make_uint2(pack_bf2(v0, v1), pack_bf2(v2, v3));
        }

    // ---- stage 2: acc2 = W2 · a  (B-frags read back from abuf)
    f4 acc2[4][4];
#pragma unroll
    for (int i = 0; i < 4; ++i)
#pragma unroll
        for (int ot = 0; ot < 4; ++ot) acc2[i][ot] = (f4){0.f, 0.f, 0.f, 0.f};

#pragma unroll
    for (int kt = 0; kt < 2; ++kt) {
        const int bc2 = kt * 8 + agrp * 2;
#pragma unroll
        for (int i = 0; i < 4; ++i) {
            const uint2 rA = abuf[wid][(arow * 4 + i) * 16 + (bc2 ^ arow)];
            const uint2 rB = abuf[wid][(arow * 4 + i) * 16 + ((bc2 + 1) ^ arow)];
            int4 ti = make_int4((int)rA.x, (int)rA.y, (int)rB.x, (int)rB.y);
            bf8 bfr = __builtin_bit_cast(bf8, ti);
#pragma unroll
            for (int ot = 0; ot < 4; ++ot)
                acc2[i][ot] = __builtin_amdgcn_mfma_f32_16x16x32_bf16(afr2[ot][kt], bfr, acc2[i][ot], 0, 0, 0);
        }
    }

    // ---- epilogue: hi = tanh((acc2+b2)*0.25) * v
#pragma unroll
    for (int ot = 0; ot < 4; ++ot) {
#pragma unroll
        for (int r = 0; r < 4; ++r) {
            const int o = ot * 16 + agrp * 4 + r;
            const float bs = b2v[o];
            float4 vv4 = *(const float4*)&xv[(long long)o * NP + p0];
            float4 v;
            v.x = tanhf((acc2[0][ot][r] + bs) * 0.25f) * vv4.x;
            v.y = tanhf((acc2[1][ot][r] + bs) * 0.25f) * vv4.y;
            v.z = tanhf((acc2[2][ot][r] + bs) * 0.25f) * vv4.z;
            v.w = tanhf((acc2[3][ot][r] + bs) * 0.25f) * vv4.w;
            *(float4*)&hi[((long long)b * 128 + o) * NP + p0] = v;
        }
    }
}

// ---------------------------------------------------------------------------
// depthwise 5x5, pad 2 — LDS-staged.  (unchanged)
// ---------------------------------------------------------------------------
__global__ __launch_bounds__(256) void k_dwconv5_lds(
    const float* __restrict__ in, const float* __restrict__ w,
    const float* __restrict__ bias, float* __restrict__ out, int ch_total)
{
    __shared__ __align__(16) float img[NP];
    const int tid = threadIdx.x;
    const int ch  = blockIdx.x;
    const int b   = blockIdx.y;
    const float* ip = in + ((long long)b * ch_total + ch) * NP;

#pragma unroll
    for (int j = 0; j < 9; ++j)
        ((float4*)img)[tid + 256 * j] = ((const float4*)ip)[tid + 256 * j];
    __syncthreads();

    const float* wp = w + ch * 25;
    float wr[25];
#pragma unroll
    for (int i = 0; i < 25; ++i) wr[i] = wp[i];
    const float bs = bias[ch];

    float* op = out + ((long long)b * ch_total + ch) * NP;

#pragma unroll
    for (int j = 0; j < 9; ++j) {
        const int q  = tid + 256 * j;
        const int y  = q / 24;
        const int x4 = (q - y * 24) * 4;
        float o0 = bs, o1 = bs, o2 = bs, o3 = bs;
#pragma unroll
        for (int ky = 0; ky < 5; ++ky) {
            const int yy = y + ky - 2;
            if (yy < 0 || yy >= HH) continue;
            const float* row = &img[yy * WW + x4];
            float4 mid = *(const float4*)row;
            float4 lf  = (x4 >= 4)      ? *(const float4*)(row - 4)
                                        : make_float4(0.f, 0.f, 0.f, 0.f);
            float4 rt  = (x4 + 4 < WW)  ? *(const float4*)(row + 4)
                                        : make_float4(0.f, 0.f, 0.f, 0.f);
            const float f0 = lf.z,  f1 = lf.w;
            const float f2 = mid.x, f3 = mid.y, f4v = mid.z, f5 = mid.w;
            const float f6 = rt.x,  f7 = rt.y;
            const float w0 = wr[ky * 5 + 0], w1 = wr[ky * 5 + 1],
                        w2 = wr[ky * 5 + 2], w3 = wr[ky * 5 + 3],
                        w4 = wr[ky * 5 + 4];
            o0 = fmaf(w0, f0, o0); o0 = fmaf(w1, f1, o0); o0 = fmaf(w2, f2, o0);
            o0 = fmaf(w3, f3, o0); o0 = fmaf(w4, f4v, o0);
            o1 = fmaf(w0, f1, o1); o1 = fmaf(w1, f2, o1); o1 = fmaf(w2, f3, o1);
            o1 = fmaf(w3, f4v, o1); o1 = fmaf(w4, f5, o1);
            o2 = fmaf(w0, f2, o2); o2 = fmaf(w1, f3, o2); o2 = fmaf(w2, f4v, o2);
            o2 = fmaf(w3, f5, o2); o2 = fmaf(w4, f6, o2);
            o3 = fmaf(w0, f3, o3); o3 = fmaf(w1, f4v, o3); o3 = fmaf(w2, f5, o3);
            o3 = fmaf(w3, f6, o3); o3 = fmaf(w4, f7, o3);
        }
        *(float4*)&op[y * WW + x4] = make_float4(o0, o1, o2, o3);
    }
}

// ---------------------------------------------------------------------------
// 4x4 average pool  (unchanged)
// ---------------------------------------------------------------------------
__global__ __launch_bounds__(256) void k_avgpool4(
    const float* __restrict__ in, float* __restrict__ out)
{
    int idx = blockIdx.x * 256 + threadIdx.x;
    int total = NB * 128 * NPK;
    if (idx >= total) return;
    int pw = idx % 24;
    int t  = idx / 24;
    int ph = t % 24;  t /= 24;
    int c  = t % 128;
    int b  = t / 128;
    const float* ip = in + ((long long)b * 128 + c) * NP + (ph * 4) * WW + pw * 4;
    float s = 0.f;
#pragma unroll
    for (int i = 0; i < 4; ++i)
#pragma unroll
        for (int j = 0; j < 4; ++j) s += ip[i * WW + j];
    out[idx] = s * (1.0f / 16.0f);
}

// ---------------------------------------------------------------------------
// MFMA flash-attention — r7 verified kernel + software pipeline:
// E buffer double-buffered (elds2[2][...]); QK/exp of tile k2+1 issued before
// PV of tile k2 consumes its (already-complete) E data. Layouts identical r7.
// LDS: K 18K + z 0.5K + V^T 18K + E 16K = 52.5KB -> 3 blocks/CU (as r7).
// Grid (72, 32), 256 threads; wave = 32 q of one (b,h).
// ---------------------------------------------------------------------------
__global__ __launch_bounds__(256) void k_attn_mfma(
    const float* __restrict__ q,    // (B,64,NP)
    const float* __restrict__ kv,   // (B,128,NPK): k ch 0..63, v ch 64..127
    float* __restrict__ hilo)       // (B,128,NP), lo at ch 64..127
{
    __shared__ __align__(16) int4  klds4[36 * 32];   // [tile16][slot]  18KB
    __shared__ __align__(16) int4  zlds4[32];        // zero block      0.5KB
    __shared__ __align__(16) int4  vlds4[18 * 64];   // [tile32][lane]  18KB
    __shared__ __align__(16) uint2 elds2[2][4 * 256];// dbuf E          16KB

    const int tid  = threadIdx.x;
    const int lane = tid & 63, wid = tid >> 6;
    const int g    = lane >> 4, qi = lane & 15;
    const int bh   = blockIdx.y, b = bh >> 2, h = bh & 3;

    const float* kbase = kv + ((long long)b * 128 + h * 16) * NPK;
    const float* vbase = kv + ((long long)b * 128 + 64 + h * 16) * NPK;

    for (int i = tid; i < 1152; i += 256) {
        const int key = i >> 1, dg = i & 1;
        const float* kp = kbase + (long long)(dg * 8) * NPK + key;
        int4 t;
        t.x = (int)pack_bf2(kp[0],       kp[NPK]);
        t.y = (int)pack_bf2(kp[2 * NPK], kp[3 * NPK]);
        t.z = (int)pack_bf2(kp[4 * NPK], kp[5 * NPK]);
        t.w = (int)pack_bf2(kp[6 * NPK], kp[7 * NPK]);
        klds4[(key >> 4) * 32 + dg * 16 + (key & 15)] = t;
    }
    for (int i = tid; i < 1152; i += 256) {
        const int t = i >> 6, l = i & 63;
        const float* vp = vbase + (long long)(l & 15) * NPK + t * 32 + (l >> 4) * 8;
        float4 a = *(const float4*)vp;
        float4 c = *(const float4*)(vp + 4);
        int4 tt;
        tt.x = (int)pack_bf2(a.x, a.y);
        tt.y = (int)pack_bf2(a.z, a.w);
        tt.z = (int)pack_bf2(c.x, c.y);
        tt.w = (int)pack_bf2(c.z, c.w);
        vlds4[i] = tt;
    }
    if (tid < 32) zlds4[tid] = make_int4(0, 0, 0, 0);
    __syncthreads();

    const int q0 = (blockIdx.x * 4 + wid) * 32;
    const float* qcol = q + ((long long)b * 64 + h * 16) * NP + q0 + qi;
    int4 qv[2] = { make_int4(0, 0, 0, 0), make_int4(0, 0, 0, 0) };
    if (g < 2) {
#pragma unroll
        for (int s = 0; s < 2; ++s) {
            const float* qp = qcol + s * 16 + (long long)(g * 8) * NP;
            qv[s].x = (int)pack_bf2(qp[0]        * 0.25f, qp[(long long)NP] * 0.25f);
            qv[s].y = (int)pack_bf2(qp[2ll * NP] * 0.25f, qp[3ll * NP]      * 0.25f);
            qv[s].z = (int)pack_bf2(qp[4ll * NP] * 0.25f, qp[5ll * NP]      * 0.25f);
            qv[s].w = (int)pack_bf2(qp[6ll * NP] * 0.25f, qp[7ll * NP]      * 0.25f);
        }
    }

    f4 accp[2] = { (f4){0.f, 0.f, 0.f, 0.f}, (f4){0.f, 0.f, 0.f, 0.f} };
    float den[2] = { 0.f, 0.f };

    auto QKEXP = [&](int k2, int buf) {
#pragma unroll
        for (int tp = 0; tp < 2; ++tp) {
            const int4 kf = (lane < 32) ? klds4[(k2 * 2 + tp) * 32 + lane]
                                        : zlds4[lane & 31];
            const bf8 ka = __builtin_bit_cast(bf8, kf);
#pragma unroll
            for (int s = 0; s < 2; ++s) {
                f4 sa = __builtin_amdgcn_mfma_f32_16x16x32_bf16(
                    ka, __builtin_bit_cast(bf8, qv[s]), (f4){0.f, 0.f, 0.f, 0.f}, 0, 0, 0);
                const float e0 = __expf(sa[0]), e1 = __expf(sa[1]);
                const float e2 = __expf(sa[2]), e3 = __expf(sa[3]);
                den[s] += (e0 + e1) + (e2 + e3);
                elds2[buf][wid * 256 + s * 128 + tp * 64 + g * 16 + qi] =
                    make_uint2(pack_bf2(e0, e1), pack_bf2(e2, e3));
            }
        }
    };
    auto PV = [&](int k2, int buf) {
        const bf8 va = __builtin_bit_cast(bf8, vlds4[k2 * 64 + lane]);
#pragma unroll
        for (int s = 0; s < 2; ++s) {
            const int base = wid * 256 + s * 128 + (g >> 1) * 64 + (g & 1) * 32 + qi;
            const uint2 r0 = elds2[buf][base];
            const uint2 r1 = elds2[buf][base + 16];
            int4 ti = make_int4((int)r0.x, (int)r0.y, (int)r1.x, (int)r1.y);
            accp[s] = __builtin_amdgcn_mfma_f32_16x16x32_bf16(
                va, __builtin_bit_cast(bf8, ti), accp[s], 0, 0, 0);
        }
    };

    QKEXP(0, 0);
    for (int k2 = 0; k2 < 17; ++k2) {
        QKEXP(k2 + 1, (k2 + 1) & 1);   // fill next buffer
        PV(k2, k2 & 1);                // consume current (written last iter)
    }
    PV(17, 1);

#pragma unroll
    for (int s = 0; s < 2; ++s) {
        float d0 = den[s];
        d0 += __shfl_xor(d0, 16, 64);
        d0 += __shfl_xor(d0, 32, 64);
        const float inv = 1.0f / d0;
        float* op = hilo + ((long long)b * 128 + 64 + h * 16 + g * 4) * NP + q0 + s * 16 + qi;
#pragma unroll
        for (int r = 0; r < 4; ++r)
            op[(long long)r * NP] = accp[s][r] * inv;
    }
}

// ---------------------------------------------------------------------------
extern "C" void kernel_launch(void* const* d_in, const int* in_sizes, int n_in,
                              void* d_out, int out_size, void* d_ws, size_t ws_size,
                              hipStream_t stream)
{
    const float* x      = (const float*)d_in[0];
    const float* qkv_w  = (const float*)d_in[1];
    const float* qkv_b  = (const float*)d_in[2];
    const float* dw_w   = (const float*)d_in[3];
    const float* dw_b   = (const float*)d_in[4];
    const float* am_w1  = (const float*)d_in[5];
    const float* am_b1  = (const float*)d_in[6];
    const float* am_w2  = (const float*)d_in[7];
    const float* am_b2  = (const float*)d_in[8];
    const float* gq_w   = (const float*)d_in[9];
    const float* gq_b   = (const float*)d_in[10];
    const float* gkv_w  = (const float*)d_in[11];
    const float* gkv_b  = (const float*)d_in[12];
    const float* proj_w = (const float*)d_in[13];
    const float* proj_b = (const float*)d_in[14];
    float* out = (float*)d_out;
    float* ws  = (float*)d_ws;

    float* t_qkv  = ws;                     // (8,192,9216)
    float* t_hilo = ws;                     // (8,128,9216): hi ch 0..63, lo 64..127
    float* t_dw   = ws + 14155776;          // (8,192,9216)
    float* t_gq   = ws + 28311552;          // (8,64,9216)
    float* t_pool = ws + 33030144;          // (8,128,576)
    float* t_gkv  = ws + 33619968;          // (8,128,576)

    const long long ibs_x = (long long)128 * NP;

    // 1. qkv = conv1x1(x)                        (8,192,96,96)
    k_mfma_conv<128,4,0,0><<<dim3(36,3,NB), 256, 0, stream>>>(
        x, nullptr, qkv_w, qkv_b, t_qkv, NP, ibs_x, 0, 192, 1);
    // 2. depthwise 5x5 (LDS-staged)
    k_dwconv5_lds<<<dim3(192, NB), 256, 0, stream>>>(t_qkv, dw_w, dw_b, t_dw, 192);
    // 3. gq = conv1x1(x)                         (8,64,96,96)
    k_mfma_conv<128,4,0,0><<<dim3(36,1,NB), 256, 0, stream>>>(
        x, nullptr, gq_w, gq_b, t_gq, NP, ibs_x, 0, 64, 1);
    // 4. pooled = avgpool4(x)                    (8,128,24,24)
    k_avgpool4<<<dim3((NB*128*NPK + 255)/256), 256, 0, stream>>>(x, t_pool);
    // 5. gkv = conv1x1(pooled)                   (8,128,24,24)
    k_mfma_conv<128,4,0,0><<<dim3(3,2,NB), 256, 0, stream>>>(
        t_pool, nullptr, gkv_w, gkv_b, t_gkv, NPK, (long long)128 * NPK, 0, 128, 1);
    // 6+7. fused am: hi = tanh((W2·silu(W1·(q∘k))+b2)/4)·v -> hilo ch 0..63
    k_am_fused<<<dim3(36,1,NB), 256, 0, stream>>>(
        t_dw, am_w1, am_b1, am_w2, am_b2, t_hilo);
    // 8. lo = MFMA flash attention(gq, gkv)      -> hilo ch 64..127
    k_attn_mfma<<<dim3(72, 32), 256, 0, stream>>>(t_gq, t_gkv, t_hilo);
    // 9. out = conv1x1(hilo, proj_w)
    k_mfma_conv<128,4,0,0><<<dim3(36,2,NB), 256, 0, stream>>>(
        t_hilo, nullptr, proj_w, proj_b, out, NP, ibs_x, 0, 128, 1);
}

// Round 11
// 188.325 us; speedup vs baseline: 1.2007x; 1.1658x over previous
//
#include <hip/hip_runtime.h>
#include <hip/hip_bf16.h>
#include <hip/hip_fp16.h>
#include <cstdint>

static constexpr int NB  = 8;
static constexpr int HH  = 96;
static constexpr int WW  = 96;
static constexpr int NP  = 9216;   // 96*96
static constexpr int NPK = 576;    // 24*24

using bf8 = __attribute__((ext_vector_type(8))) short;
using f4  = __attribute__((ext_vector_type(4))) float;

__device__ __forceinline__ unsigned pack_bf2(float a, float b) {
    __hip_bfloat162 h = __float22bfloat162_rn(make_float2(a, b));
    unsigned u; __builtin_memcpy(&u, &h, 4);
    return u;
}
__device__ __forceinline__ unsigned short f2bfu(float f) {
    __hip_bfloat16 h = __float2bfloat16(f);
    unsigned short u; __builtin_memcpy(&u, &h, 2);
    return u;
}
__device__ __forceinline__ float bf2f(unsigned short u) {
    unsigned v = (unsigned)u << 16;
    float f; __builtin_memcpy(&f, &v, 4);
    return f;
}

// ---------------------------------------------------------------------------
// MFMA conv1x1, 4-pixel-per-lane vectorized.  INBF/OUTBF select f32 or bf16
// storage for input/output (bf16 in = pre-packed pairs via OR/SHL, no cvt).
// ---------------------------------------------------------------------------
template<int C, int OT, int INBF, int OUTBF>
__global__ __launch_bounds__(256) void k_mfma_conv(
    const void* __restrict__ in0v, const float* __restrict__ w,
    const float* __restrict__ bias, void* __restrict__ outv,
    int np, long long ibs, int storeO, float wscale)
{
    constexpr int KT = C / 32;
    const int tid  = threadIdx.x;
    const int lane = tid & 63, wid = tid >> 6;
    const int b    = blockIdx.z;
    const int obq  = blockIdx.y * (OT * 16);
    const int arow = lane & 15, agrp = lane >> 4;
    const int nquad = np >> 6;

    bf8 afr[OT][KT];
#pragma unroll
    for (int ot = 0; ot < OT; ++ot)
#pragma unroll
        for (int kt = 0; kt < KT; ++kt) {
            const float* wp = w + (long long)(obq + ot * 16 + arow) * C + kt * 32 + agrp * 8;
            int4 t;
            t.x = (int)pack_bf2(wp[0] * wscale, wp[1] * wscale);
            t.y = (int)pack_bf2(wp[2] * wscale, wp[3] * wscale);
            t.z = (int)pack_bf2(wp[4] * wscale, wp[5] * wscale);
            t.w = (int)pack_bf2(wp[6] * wscale, wp[7] * wscale);
            afr[ot][kt] = __builtin_bit_cast(bf8, t);
        }

    const float*          x0f = (const float*)in0v          + (long long)b * (INBF ? 0 : ibs);
    const unsigned short* x0h = (const unsigned short*)in0v + (long long)b * (INBF ? ibs : 0);

    const int quad = blockIdx.x * 4 + wid;
    if (quad >= nquad) return;
    const int p0 = quad * 64 + arow * 4;

    f4 acc[4][OT];
#pragma unroll
    for (int i = 0; i < 4; ++i)
#pragma unroll
        for (int ot = 0; ot < OT; ++ot) acc[i][ot] = (f4){0.f, 0.f, 0.f, 0.f};

#pragma unroll
    for (int kt = 0; kt < KT; ++kt) {
        const long long cbase = kt * 32 + agrp * 8;
        int uu[4][4];
#pragma unroll
        for (int jj = 0; jj < 4; ++jj) {
            if (INBF == 0) {
                float4 a0 = *(const float4*)&x0f[(cbase + 2 * jj) * np + p0];
                float4 a1 = *(const float4*)&x0f[(cbase + 2 * jj + 1) * np + p0];
                uu[0][jj] = (int)pack_bf2(a0.x, a1.x);
                uu[1][jj] = (int)pack_bf2(a0.y, a1.y);
                uu[2][jj] = (int)pack_bf2(a0.z, a1.z);
                uu[3][jj] = (int)pack_bf2(a0.w, a1.w);
            } else {
                ushort4 a0 = *(const ushort4*)&x0h[(cbase + 2 * jj) * np + p0];
                ushort4 a1 = *(const ushort4*)&x0h[(cbase + 2 * jj + 1) * np + p0];
                uu[0][jj] = (int)((unsigned)a0.x | ((unsigned)a1.x << 16));
                uu[1][jj] = (int)((unsigned)a0.y | ((unsigned)a1.y << 16));
                uu[2][jj] = (int)((unsigned)a0.z | ((unsigned)a1.z << 16));
                uu[3][jj] = (int)((unsigned)a0.w | ((unsigned)a1.w << 16));
            }
        }
#pragma unroll
        for (int i = 0; i < 4; ++i) {
            int4 ti = {uu[i][0], uu[i][1], uu[i][2], uu[i][3]};
            bf8 bfr = __builtin_bit_cast(bf8, ti);
#pragma unroll
            for (int ot = 0; ot < OT; ++ot)
                acc[i][ot] = __builtin_amdgcn_mfma_f32_16x16x32_bf16(afr[ot][kt], bfr, acc[i][ot], 0, 0, 0);
        }
    }

#pragma unroll
    for (int ot = 0; ot < OT; ++ot) {
#pragma unroll
        for (int r = 0; r < 4; ++r) {
            const int o = obq + ot * 16 + agrp * 4 + r;
            const float bs = bias[o] * wscale;
            float4 v;
            v.x = acc[0][ot][r] + bs;
            v.y = acc[1][ot][r] + bs;
            v.z = acc[2][ot][r] + bs;
            v.w = acc[3][ot][r] + bs;
            const long long idx = ((long long)b * storeO + o) * np + p0;
            if (OUTBF == 0) {
                *(float4*)&((float*)outv)[idx] = v;
            } else {
                *(uint2*)&((unsigned short*)outv)[idx] =
                    make_uint2(pack_bf2(v.x, v.y), pack_bf2(v.z, v.w));
            }
        }
    }
}

// ---------------------------------------------------------------------------
// Fused am1+am2 (bf16 I/O): a = silu(W1·(q̃∘k̃)+b1); hi = tanh((W2·a+b2)/4)·ṽ.
// Per-wave LDS relayout for a (XOR-swizzled), unchanged from r10.
// ---------------------------------------------------------------------------
__global__ __launch_bounds__(256) void k_am_fused(
    const unsigned short* __restrict__ dw,   // bf16: q +0, k +64NP, v +128NP
    const float* __restrict__ w1, const float* __restrict__ b1v,
    const float* __restrict__ w2, const float* __restrict__ b2v,
    unsigned short* __restrict__ hi)         // bf16 hilo ch 0..63
{
    __shared__ __align__(16) uint2 abuf[4][1024];

    const int tid  = threadIdx.x;
    const int lane = tid & 63, wid = tid >> 6;
    const int b    = blockIdx.z;
    const int arow = lane & 15, agrp = lane >> 4;

    bf8 afr1[4][2], afr2[4][2];
#pragma unroll
    for (int ot = 0; ot < 4; ++ot)
#pragma unroll
        for (int kt = 0; kt < 2; ++kt) {
            const float* wp1 = w1 + (long long)(ot * 16 + arow) * 64 + kt * 32 + agrp * 8;
            const float* wp2 = w2 + (long long)(ot * 16 + arow) * 64 + kt * 32 + agrp * 8;
            int4 t1, t2;
            t1.x = (int)pack_bf2(wp1[0], wp1[1]);  t2.x = (int)pack_bf2(wp2[0], wp2[1]);
            t1.y = (int)pack_bf2(wp1[2], wp1[3]);  t2.y = (int)pack_bf2(wp2[2], wp2[3]);
            t1.z = (int)pack_bf2(wp1[4], wp1[5]);  t2.z = (int)pack_bf2(wp2[4], wp2[5]);
            t1.w = (int)pack_bf2(wp1[6], wp1[7]);  t2.w = (int)pack_bf2(wp2[6], wp2[7]);
            afr1[ot][kt] = __builtin_bit_cast(bf8, t1);
            afr2[ot][kt] = __builtin_bit_cast(bf8, t2);
        }

    const unsigned short* xq = dw + (long long)b * (192ll * NP);
    const unsigned short* xk = xq + 64ll * NP;
    const unsigned short* xv = xq + 128ll * NP;

    const int quad = blockIdx.x * 4 + wid;
    const int p0 = quad * 64 + arow * 4;

    f4 acc1[4][4];
#pragma unroll
    for (int i = 0; i < 4; ++i)
#pragma unroll
        for (int ot = 0; ot < 4; ++ot) acc1[i][ot] = (f4){0.f, 0.f, 0.f, 0.f};

#pragma unroll
    for (int kt = 0; kt < 2; ++kt) {
        const long long cbase = kt * 32 + agrp * 8;
        int uu[4][4];
#pragma unroll
        for (int jj = 0; jj < 4; ++jj) {
            ushort4 a0 = *(const ushort4*)&xq[(cbase + 2 * jj) * NP + p0];
            ushort4 a1 = *(const ushort4*)&xq[(cbase + 2 * jj + 1) * NP + p0];
            ushort4 y0 = *(const ushort4*)&xk[(cbase + 2 * jj) * NP + p0];
            ushort4 y1 = *(const ushort4*)&xk[(cbase + 2 * jj + 1) * NP + p0];
            uu[0][jj] = (int)pack_bf2(bf2f(a0.x) * bf2f(y0.x), bf2f(a1.x) * bf2f(y1.x));
            uu[1][jj] = (int)pack_bf2(bf2f(a0.y) * bf2f(y0.y), bf2f(a1.y) * bf2f(y1.y));
            uu[2][jj] = (int)pack_bf2(bf2f(a0.z) * bf2f(y0.z), bf2f(a1.z) * bf2f(y1.z));
            uu[3][jj] = (int)pack_bf2(bf2f(a0.w) * bf2f(y0.w), bf2f(a1.w) * bf2f(y1.w));
        }
#pragma unroll
        for (int i = 0; i < 4; ++i) {
            int4 ti = {uu[i][0], uu[i][1], uu[i][2], uu[i][3]};
            bf8 bfr = __builtin_bit_cast(bf8, ti);
#pragma unroll
            for (int ot = 0; ot < 4; ++ot)
                acc1[i][ot] = __builtin_amdgcn_mfma_f32_16x16x32_bf16(afr1[ot][kt], bfr, acc1[i][ot], 0, 0, 0);
        }
    }

#pragma unroll
    for (int i = 0; i < 4; ++i)
#pragma unroll
        for (int ot = 0; ot < 4; ++ot) {
            const int ch0 = ot * 16 + agrp * 4;
            float v0 = acc1[i][ot][0] + b1v[ch0 + 0];
            float v1 = acc1[i][ot][1] + b1v[ch0 + 1];
            float v2 = acc1[i][ot][2] + b1v[ch0 + 2];
            float v3 = acc1[i][ot][3] + b1v[ch0 + 3];
            v0 = v0 / (1.f + __expf(-v0));
            v1 = v1 / (1.f + __expf(-v1));
            v2 = v2 / (1.f + __expf(-v2));
            v3 = v3 / (1.f + __expf(-v3));
            const int c2 = ot * 4 + agrp;
            abuf[wid][(arow * 4 + i) * 16 + (c2 ^ arow)] =
                make_uint2(pack_bf2(v0, v1), pack_bf2(v2, v3));
        }

    f4 acc2[4][4];
#pragma unroll
    for (int i = 0; i < 4; ++i)
#pragma unroll
        for (int ot = 0; ot < 4; ++ot) acc2[i][ot] = (f4){0.f, 0.f, 0.f, 0.f};

#pragma unroll
    for (int kt = 0; kt < 2; ++kt) {
        const int bc2 = kt * 8 + agrp * 2;
#pragma unroll
        for (int i = 0; i < 4; ++i) {
            const uint2 rA = abuf[wid][(arow * 4 + i) * 16 + (bc2 ^ arow)];
            const uint2 rB = abuf[wid][(arow * 4 + i) * 16 + ((bc2 + 1) ^ arow)];
            int4 ti = make_int4((int)rA.x, (int)rA.y, (int)rB.x, (int)rB.y);
            bf8 bfr = __builtin_bit_cast(bf8, ti);
#pragma unroll
            for (int ot = 0; ot < 4; ++ot)
                acc2[i][ot] = __builtin_amdgcn_mfma_f32_16x16x32_bf16(afr2[ot][kt], bfr, acc2[i][ot], 0, 0, 0);
        }
    }

#pragma unroll
    for (int ot = 0; ot < 4; ++ot) {
#pragma unroll
        for (int r = 0; r < 4; ++r) {
            const int o = ot * 16 + agrp * 4 + r;
            const float bs = b2v[o];
            ushort4 vv4 = *(const ushort4*)&xv[(long long)o * NP + p0];
            float h0 = tanhf((acc2[0][ot][r] + bs) * 0.25f) * bf2f(vv4.x);
            float h1 = tanhf((acc2[1][ot][r] + bs) * 0.25f) * bf2f(vv4.y);
            float h2 = tanhf((acc2[2][ot][r] + bs) * 0.25f) * bf2f(vv4.z);
            float h3 = tanhf((acc2[3][ot][r] + bs) * 0.25f) * bf2f(vv4.w);
            *(uint2*)&hi[((long long)b * 128 + o) * NP + p0] =
                make_uint2(pack_bf2(h0, h1), pack_bf2(h2, h3));
        }
    }
}

// ---------------------------------------------------------------------------
// depthwise 5x5, pad 2 — LDS-staged; bf16 output.
// ---------------------------------------------------------------------------
__global__ __launch_bounds__(256) void k_dwconv5_lds(
    const float* __restrict__ in, const float* __restrict__ w,
    const float* __restrict__ bias, unsigned short* __restrict__ out, int ch_total)
{
    __shared__ __align__(16) float img[NP];
    const int tid = threadIdx.x;
    const int ch  = blockIdx.x;
    const int b   = blockIdx.y;
    const float* ip = in + ((long long)b * ch_total + ch) * NP;

#pragma unroll
    for (int j = 0; j < 9; ++j)
        ((float4*)img)[tid + 256 * j] = ((const float4*)ip)[tid + 256 * j];
    __syncthreads();

    const float* wp = w + ch * 25;
    float wr[25];
#pragma unroll
    for (int i = 0; i < 25; ++i) wr[i] = wp[i];
    const float bs = bias[ch];

    unsigned short* op = out + ((long long)b * ch_total + ch) * NP;

#pragma unroll
    for (int j = 0; j < 9; ++j) {
        const int q  = tid + 256 * j;
        const int y  = q / 24;
        const int x4 = (q - y * 24) * 4;
        float o0 = bs, o1 = bs, o2 = bs, o3 = bs;
#pragma unroll
        for (int ky = 0; ky < 5; ++ky) {
            const int yy = y + ky - 2;
            if (yy < 0 || yy >= HH) continue;
            const float* row = &img[yy * WW + x4];
            float4 mid = *(const float4*)row;
            float4 lf  = (x4 >= 4)      ? *(const float4*)(row - 4)
                                        : make_float4(0.f, 0.f, 0.f, 0.f);
            float4 rt  = (x4 + 4 < WW)  ? *(const float4*)(row + 4)
                                        : make_float4(0.f, 0.f, 0.f, 0.f);
            const float f0 = lf.z,  f1 = lf.w;
            const float f2 = mid.x, f3 = mid.y, f4v = mid.z, f5 = mid.w;
            const float f6 = rt.x,  f7 = rt.y;
            const float w0 = wr[ky * 5 + 0], w1 = wr[ky * 5 + 1],
                        w2 = wr[ky * 5 + 2], w3 = wr[ky * 5 + 3],
                        w4 = wr[ky * 5 + 4];
            o0 = fmaf(w0, f0, o0); o0 = fmaf(w1, f1, o0); o0 = fmaf(w2, f2, o0);
            o0 = fmaf(w3, f3, o0); o0 = fmaf(w4, f4v, o0);
            o1 = fmaf(w0, f1, o1); o1 = fmaf(w1, f2, o1); o1 = fmaf(w2, f3, o1);
            o1 = fmaf(w3, f4v, o1); o1 = fmaf(w4, f5, o1);
            o2 = fmaf(w0, f2, o2); o2 = fmaf(w1, f3, o2); o2 = fmaf(w2, f4v, o2);
            o2 = fmaf(w3, f5, o2); o2 = fmaf(w4, f6, o2);
            o3 = fmaf(w0, f3, o3); o3 = fmaf(w1, f4v, o3); o3 = fmaf(w2, f5, o3);
            o3 = fmaf(w3, f6, o3); o3 = fmaf(w4, f7, o3);
        }
        *(uint2*)&op[y * WW + x4] = make_uint2(pack_bf2(o0, o1), pack_bf2(o2, o3));
    }
}

// ---------------------------------------------------------------------------
// 4x4 average pool  (unchanged, f32)
// ---------------------------------------------------------------------------
__global__ __launch_bounds__(256) void k_avgpool4(
    const float* __restrict__ in, float* __restrict__ out)
{
    int idx = blockIdx.x * 256 + threadIdx.x;
    int total = NB * 128 * NPK;
    if (idx >= total) return;
    int pw = idx % 24;
    int t  = idx / 24;
    int ph = t % 24;  t /= 24;
    int c  = t % 128;
    int b  = t / 128;
    const float* ip = in + ((long long)b * 128 + c) * NP + (ph * 4) * WW + pw * 4;
    float s = 0.f;
#pragma unroll
    for (int i = 0; i < 4; ++i)
#pragma unroll
        for (int j = 0; j < 4; ++j) s += ip[i * WW + j];
    out[idx] = s * (1.0f / 16.0f);
}

// ---------------------------------------------------------------------------
// MFMA flash-attention — r10 structure; q input is pre-scaled bf16 (OR/SHL
// frag build, no cvt), lo output stored bf16.
// ---------------------------------------------------------------------------
__global__ __launch_bounds__(256) void k_attn_mfma(
    const unsigned short* __restrict__ q,  // bf16 (B,64,NP), pre-scaled by 0.25
    const float* __restrict__ kv,          // f32 (B,128,NPK)
    unsigned short* __restrict__ hilo)     // bf16 (B,128,NP), lo at ch 64..127
{
    __shared__ __align__(16) int4  klds4[36 * 32];
    __shared__ __align__(16) int4  zlds4[32];
    __shared__ __align__(16) int4  vlds4[18 * 64];
    __shared__ __align__(16) uint2 elds2[2][4 * 256];

    const int tid  = threadIdx.x;
    const int lane = tid & 63, wid = tid >> 6;
    const int g    = lane >> 4, qi = lane & 15;
    const int bh   = blockIdx.y, b = bh >> 2, h = bh & 3;

    const float* kbase = kv + ((long long)b * 128 + h * 16) * NPK;
    const float* vbase = kv + ((long long)b * 128 + 64 + h * 16) * NPK;

    for (int i = tid; i < 1152; i += 256) {
        const int key = i >> 1, dg = i & 1;
        const float* kp = kbase + (long long)(dg * 8) * NPK + key;
        int4 t;
        t.x = (int)pack_bf2(kp[0],       kp[NPK]);
        t.y = (int)pack_bf2(kp[2 * NPK], kp[3 * NPK]);
        t.z = (int)pack_bf2(kp[4 * NPK], kp[5 * NPK]);
        t.w = (int)pack_bf2(kp[6 * NPK], kp[7 * NPK]);
        klds4[(key >> 4) * 32 + dg * 16 + (key & 15)] = t;
    }
    for (int i = tid; i < 1152; i += 256) {
        const int t = i >> 6, l = i & 63;
        const float* vp = vbase + (long long)(l & 15) * NPK + t * 32 + (l >> 4) * 8;
        float4 a = *(const float4*)vp;
        float4 c = *(const float4*)(vp + 4);
        int4 tt;
        tt.x = (int)pack_bf2(a.x, a.y);
        tt.y = (int)pack_bf2(a.z, a.w);
        tt.z = (int)pack_bf2(c.x, c.y);
        tt.w = (int)pack_bf2(c.z, c.w);
        vlds4[i] = tt;
    }
    if (tid < 32) zlds4[tid] = make_int4(0, 0, 0, 0);
    __syncthreads();

    const int q0 = (blockIdx.x * 4 + wid) * 32;
    const unsigned short* qcol = q + ((long long)b * 64 + h * 16) * NP + q0 + qi;
    int4 qv[2] = { make_int4(0, 0, 0, 0), make_int4(0, 0, 0, 0) };
    if (g < 2) {
#pragma unroll
        for (int s = 0; s < 2; ++s) {
            const unsigned short* qp = qcol + s * 16 + (long long)(g * 8) * NP;
            qv[s].x = (int)((unsigned)qp[0]          | ((unsigned)qp[(long long)NP]     << 16));
            qv[s].y = (int)((unsigned)qp[2ll * NP]   | ((unsigned)qp[3ll * NP]          << 16));
            qv[s].z = (int)((unsigned)qp[4ll * NP]   | ((unsigned)qp[5ll * NP]          << 16));
            qv[s].w = (int)((unsigned)qp[6ll * NP]   | ((unsigned)qp[7ll * NP]          << 16));
        }
    }

    f4 accp[2] = { (f4){0.f, 0.f, 0.f, 0.f}, (f4){0.f, 0.f, 0.f, 0.f} };
    float den[2] = { 0.f, 0.f };

    auto QKEXP = [&](int k2, int buf) {
#pragma unroll
        for (int tp = 0; tp < 2; ++tp) {
            const int4 kf = (lane < 32) ? klds4[(k2 * 2 + tp) * 32 + lane]
                                        : zlds4[lane & 31];
            const bf8 ka = __builtin_bit_cast(bf8, kf);
#pragma unroll
            for (int s = 0; s < 2; ++s) {
                f4 sa = __builtin_amdgcn_mfma_f32_16x16x32_bf16(
                    ka, __builtin_bit_cast(bf8, qv[s]), (f4){0.f, 0.f, 0.f, 0.f}, 0, 0, 0);
                const float e0 = __expf(sa[0]), e1 = __expf(sa[1]);
                const float e2 = __expf(sa[2]), e3 = __expf(sa[3]);
                den[s] += (e0 + e1) + (e2 + e3);
                elds2[buf][wid * 256 + s * 128 + tp * 64 + g * 16 + qi] =
                    make_uint2(pack_bf2(e0, e1), pack_bf2(e2, e3));
            }
        }
    };
    auto PV = [&](int k2, int buf) {
        const bf8 va = __builtin_bit_cast(bf8, vlds4[k2 * 64 + lane]);
#pragma unroll
        for (int s = 0; s < 2; ++s) {
            const int base = wid * 256 + s * 128 + (g >> 1) * 64 + (g & 1) * 32 + qi;
            const uint2 r0 = elds2[buf][base];
            const uint2 r1 = elds2[buf][base + 16];
            int4 ti = make_int4((int)r0.x, (int)r0.y, (int)r1.x, (int)r1.y);
            accp[s] = __builtin_amdgcn_mfma_f32_16x16x32_bf16(
                va, __builtin_bit_cast(bf8, ti), accp[s], 0, 0, 0);
        }
    };

    QKEXP(0, 0);
    for (int k2 = 0; k2 < 17; ++k2) {
        QKEXP(k2 + 1, (k2 + 1) & 1);
        PV(k2, k2 & 1);
    }
    PV(17, 1);

#pragma unroll
    for (int s = 0; s < 2; ++s) {
        float d0 = den[s];
        d0 += __shfl_xor(d0, 16, 64);
        d0 += __shfl_xor(d0, 32, 64);
        const float inv = 1.0f / d0;
        unsigned short* op = hilo + ((long long)b * 128 + 64 + h * 16 + g * 4) * NP + q0 + s * 16 + qi;
#pragma unroll
        for (int r = 0; r < 4; ++r)
            op[(long long)r * NP] = f2bfu(accp[s][r] * inv);
    }
}

// ---------------------------------------------------------------------------
extern "C" void kernel_launch(void* const* d_in, const int* in_sizes, int n_in,
                              void* d_out, int out_size, void* d_ws, size_t ws_size,
                              hipStream_t stream)
{
    const float* x      = (const float*)d_in[0];
    const float* qkv_w  = (const float*)d_in[1];
    const float* qkv_b  = (const float*)d_in[2];
    const float* dw_w   = (const float*)d_in[3];
    const float* dw_b   = (const float*)d_in[4];
    const float* am_w1  = (const float*)d_in[5];
    const float* am_b1  = (const float*)d_in[6];
    const float* am_w2  = (const float*)d_in[7];
    const float* am_b2  = (const float*)d_in[8];
    const float* gq_w   = (const float*)d_in[9];
    const float* gq_b   = (const float*)d_in[10];
    const float* gkv_w  = (const float*)d_in[11];
    const float* gkv_b  = (const float*)d_in[12];
    const float* proj_w = (const float*)d_in[13];
    const float* proj_b = (const float*)d_in[14];
    float* out = (float*)d_out;
    float* ws_f = (float*)d_ws;

    // workspace: t_qkv f32 [0,14155776) dead after dwconv; t_hilo bf16 reuses it
    float*          t_qkv  = ws_f;                                   // f32 (8,192,9216)
    unsigned short* t_hilo = (unsigned short*)d_ws;                  // bf16 (8,128,9216)
    unsigned short* t_dw   = (unsigned short*)(ws_f + 14155776);     // bf16 (8,192,9216)
    unsigned short* t_gq   = (unsigned short*)(ws_f + 21233664);     // bf16 (8,64,9216)
    float*          t_pool = ws_f + 23592960;                        // f32 (8,128,576)
    float*          t_gkv  = ws_f + 24182784;                        // f32 (8,128,576)

    const long long ibs_x = (long long)128 * NP;

    // 1. qkv = conv1x1(x)                        f32 out
    k_mfma_conv<128,4,0,0><<<dim3(36,3,NB), 256, 0, stream>>>(
        x, qkv_w, qkv_b, t_qkv, NP, ibs_x, 192, 1.0f);
    // 2. depthwise 5x5 -> bf16
    k_dwconv5_lds<<<dim3(192, NB), 256, 0, stream>>>(t_qkv, dw_w, dw_b, t_dw, 192);
    // 3. gq = conv1x1(x) * 0.25 -> bf16 (scale folded into weights/bias)
    k_mfma_conv<128,4,0,1><<<dim3(36,1,NB), 256, 0, stream>>>(
        x, gq_w, gq_b, t_gq, NP, ibs_x, 64, 0.25f);
    // 4. pooled = avgpool4(x)
    k_avgpool4<<<dim3((NB*128*NPK + 255)/256), 256, 0, stream>>>(x, t_pool);
    // 5. gkv = conv1x1(pooled)                   f32 out
    k_mfma_conv<128,4,0,0><<<dim3(3,2,NB), 256, 0, stream>>>(
        t_pool, gkv_w, gkv_b, t_gkv, NPK, (long long)128 * NPK, 128, 1.0f);
    // 6. fused am -> hilo ch 0..63 (bf16)
    k_am_fused<<<dim3(36,1,NB), 256, 0, stream>>>(
        t_dw, am_w1, am_b1, am_w2, am_b2, t_hilo);
    // 7. attention -> hilo ch 64..127 (bf16)
    k_attn_mfma<<<dim3(72, 32), 256, 0, stream>>>(t_gq, t_gkv, t_hilo);
    // 8. out = conv1x1(hilo bf16, proj_w)        f32 out
    k_mfma_conv<128,4,1,0><<<dim3(36,2,NB), 256, 0, stream>>>(
        t_hilo, proj_w, proj_b, out, NP, ibs_x, 128, 1.0f);
}

// Round 12
// 172.220 us; speedup vs baseline: 1.3130x; 1.0935x over previous
//
#include <hip/hip_runtime.h>
#include <hip/hip_bf16.h>
#include <hip/hip_fp16.h>
#include <cstdint>

static constexpr int NB  = 8;
static constexpr int HH  = 96;
static constexpr int WW  = 96;
static constexpr int NP  = 9216;   // 96*96
static constexpr int NPK = 576;    // 24*24

using bf8 = __attribute__((ext_vector_type(8))) short;
using f4  = __attribute__((ext_vector_type(4))) float;

__device__ __forceinline__ unsigned pack_bf2(float a, float b) {
    __hip_bfloat162 h = __float22bfloat162_rn(make_float2(a, b));
    unsigned u; __builtin_memcpy(&u, &h, 4);
    return u;
}
__device__ __forceinline__ unsigned short f2bfu(float f) {
    __hip_bfloat16 h = __float2bfloat16(f);
    unsigned short u; __builtin_memcpy(&u, &h, 2);
    return u;
}
__device__ __forceinline__ float bf2f(unsigned short u) {
    unsigned v = (unsigned)u << 16;
    float f; __builtin_memcpy(&f, &v, 4);
    return f;
}
__device__ __forceinline__ float bflo(unsigned p) {
    unsigned v = p << 16; float f; __builtin_memcpy(&f, &v, 4); return f;
}
__device__ __forceinline__ float bfhi(unsigned p) {
    unsigned v = p & 0xffff0000u; float f; __builtin_memcpy(&f, &v, 4); return f;
}

// ---------------------------------------------------------------------------
// Fused qkv+gq conv1x1 with LDS-staged x.
// Block = one 64-px quad. Stage x (128 ch) as packed bf16 ch-pairs into LDS
// ([px][cp ^ ((px>>2&7)<<2)] — b128 conflict-free on read, 2/bank on write).
// Each wave computes 4 of 16 output groups (12 qkv + 4 gq*0.25) from
// register-hoisted B-frags. Outputs bf16.
// ---------------------------------------------------------------------------
__global__ __launch_bounds__(256) void k_qkvgq(
    const float* __restrict__ x,
    const float* __restrict__ qkv_w, const float* __restrict__ qkv_b,
    const float* __restrict__ gq_w,  const float* __restrict__ gq_b,
    unsigned short* __restrict__ qkv_out,   // bf16 (B,192,NP)
    unsigned short* __restrict__ gq_out)    // bf16 (B,64,NP), pre-scaled 0.25
{
    __shared__ __align__(16) unsigned xl[64 * 64];   // 16KB
    const int tid  = threadIdx.x;
    const int lane = tid & 63, wid = tid >> 6;
    const int quad = blockIdx.x, b = blockIdx.z;
    const int arow = lane & 15, agrp = lane >> 4;

    const float* xb = x + (long long)b * 128 * NP + quad * 64;

    // ---- stage: task = (cp, pixel-quad); coalesced 256B-per-channel loads
#pragma unroll
    for (int it = 0; it < 4; ++it) {
        const int task = tid + 256 * it;
        const int cp = task >> 4, pq = task & 15;
        float4 a = *(const float4*)&xb[(long long)(2 * cp) * NP + pq * 4];
        float4 c = *(const float4*)&xb[(long long)(2 * cp + 1) * NP + pq * 4];
        const int cps = cp ^ ((pq & 7) << 2);
        xl[(pq * 4 + 0) * 64 + cps] = pack_bf2(a.x, c.x);
        xl[(pq * 4 + 1) * 64 + cps] = pack_bf2(a.y, c.y);
        xl[(pq * 4 + 2) * 64 + cps] = pack_bf2(a.z, c.z);
        xl[(pq * 4 + 3) * 64 + cps] = pack_bf2(a.w, c.w);
    }
    __syncthreads();

    // ---- hoist all B-frags to registers (16 x int4)
    uint4 breg[4][4];
#pragma unroll
    for (int kt = 0; kt < 4; ++kt)
#pragma unroll
        for (int i = 0; i < 4; ++i) {
            const int px = arow * 4 + i;
            const int cp = (kt * 16 + agrp * 4) ^ ((arow & 7) << 2);
            breg[kt][i] = *(const uint4*)&xl[px * 64 + cp];
        }

    // ---- 4 output groups per wave (grp = wid + 4*gi; 12..15 are gq)
    for (int gi = 0; gi < 4; ++gi) {
        const int grp = wid + gi * 4;
        const bool isgq = grp >= 12;
        const float* wsrc = isgq ? gq_w : qkv_w;
        const float* bsrc = isgq ? gq_b : qkv_b;
        const float wsc = isgq ? 0.25f : 1.0f;
        const int och = (isgq ? grp - 12 : grp) * 16;

        bf8 afr[4];
#pragma unroll
        for (int kt = 0; kt < 4; ++kt) {
            const float* wp = wsrc + (long long)(och + arow) * 128 + kt * 32 + agrp * 8;
            int4 t;
            t.x = (int)pack_bf2(wp[0] * wsc, wp[1] * wsc);
            t.y = (int)pack_bf2(wp[2] * wsc, wp[3] * wsc);
            t.z = (int)pack_bf2(wp[4] * wsc, wp[5] * wsc);
            t.w = (int)pack_bf2(wp[6] * wsc, wp[7] * wsc);
            afr[kt] = __builtin_bit_cast(bf8, t);
        }

        f4 acc[4];
#pragma unroll
        for (int i = 0; i < 4; ++i) acc[i] = (f4){0.f, 0.f, 0.f, 0.f};
#pragma unroll
        for (int kt = 0; kt < 4; ++kt)
#pragma unroll
            for (int i = 0; i < 4; ++i)
                acc[i] = __builtin_amdgcn_mfma_f32_16x16x32_bf16(
                    afr[kt], __builtin_bit_cast(bf8, breg[kt][i]), acc[i], 0, 0, 0);

        unsigned short* ob = isgq ? gq_out : qkv_out;
        const int ostride = isgq ? 64 : 192;
#pragma unroll
        for (int r = 0; r < 4; ++r) {
            const int o = och + agrp * 4 + r;
            const float bs = bsrc[o] * wsc;
            const float v0 = acc[0][r] + bs, v1 = acc[1][r] + bs;
            const float v2 = acc[2][r] + bs, v3 = acc[3][r] + bs;
            *(uint2*)&ob[((long long)b * ostride + o) * NP + quad * 64 + arow * 4] =
                make_uint2(pack_bf2(v0, v1), pack_bf2(v2, v3));
        }
    }
}

// ---------------------------------------------------------------------------
// MFMA conv1x1 (generic; used for gkv f32->f32 and proj bf16->f32).
// ---------------------------------------------------------------------------
template<int C, int OT, int INBF, int OUTBF>
__global__ __launch_bounds__(256) void k_mfma_conv(
    const void* __restrict__ in0v, const float* __restrict__ w,
    const float* __restrict__ bias, void* __restrict__ outv,
    int np, long long ibs, int storeO, float wscale)
{
    constexpr int KT = C / 32;
    const int tid  = threadIdx.x;
    const int lane = tid & 63, wid = tid >> 6;
    const int b    = blockIdx.z;
    const int obq  = blockIdx.y * (OT * 16);
    const int arow = lane & 15, agrp = lane >> 4;
    const int nquad = np >> 6;

    bf8 afr[OT][KT];
#pragma unroll
    for (int ot = 0; ot < OT; ++ot)
#pragma unroll
        for (int kt = 0; kt < KT; ++kt) {
            const float* wp = w + (long long)(obq + ot * 16 + arow) * C + kt * 32 + agrp * 8;
            int4 t;
            t.x = (int)pack_bf2(wp[0] * wscale, wp[1] * wscale);
            t.y = (int)pack_bf2(wp[2] * wscale, wp[3] * wscale);
            t.z = (int)pack_bf2(wp[4] * wscale, wp[5] * wscale);
            t.w = (int)pack_bf2(wp[6] * wscale, wp[7] * wscale);
            afr[ot][kt] = __builtin_bit_cast(bf8, t);
        }

    const float*          x0f = (const float*)in0v          + (long long)b * (INBF ? 0 : ibs);
    const unsigned short* x0h = (const unsigned short*)in0v + (long long)b * (INBF ? ibs : 0);

    const int quad = blockIdx.x * 4 + wid;
    if (quad >= nquad) return;
    const int p0 = quad * 64 + arow * 4;

    f4 acc[4][OT];
#pragma unroll
    for (int i = 0; i < 4; ++i)
#pragma unroll
        for (int ot = 0; ot < OT; ++ot) acc[i][ot] = (f4){0.f, 0.f, 0.f, 0.f};

#pragma unroll
    for (int kt = 0; kt < KT; ++kt) {
        const long long cbase = kt * 32 + agrp * 8;
        int uu[4][4];
#pragma unroll
        for (int jj = 0; jj < 4; ++jj) {
            if (INBF == 0) {
                float4 a0 = *(const float4*)&x0f[(cbase + 2 * jj) * np + p0];
                float4 a1 = *(const float4*)&x0f[(cbase + 2 * jj + 1) * np + p0];
                uu[0][jj] = (int)pack_bf2(a0.x, a1.x);
                uu[1][jj] = (int)pack_bf2(a0.y, a1.y);
                uu[2][jj] = (int)pack_bf2(a0.z, a1.z);
                uu[3][jj] = (int)pack_bf2(a0.w, a1.w);
            } else {
                ushort4 a0 = *(const ushort4*)&x0h[(cbase + 2 * jj) * np + p0];
                ushort4 a1 = *(const ushort4*)&x0h[(cbase + 2 * jj + 1) * np + p0];
                uu[0][jj] = (int)((unsigned)a0.x | ((unsigned)a1.x << 16));
                uu[1][jj] = (int)((unsigned)a0.y | ((unsigned)a1.y << 16));
                uu[2][jj] = (int)((unsigned)a0.z | ((unsigned)a1.z << 16));
                uu[3][jj] = (int)((unsigned)a0.w | ((unsigned)a1.w << 16));
            }
        }
#pragma unroll
        for (int i = 0; i < 4; ++i) {
            int4 ti = {uu[i][0], uu[i][1], uu[i][2], uu[i][3]};
            bf8 bfr = __builtin_bit_cast(bf8, ti);
#pragma unroll
            for (int ot = 0; ot < OT; ++ot)
                acc[i][ot] = __builtin_amdgcn_mfma_f32_16x16x32_bf16(afr[ot][kt], bfr, acc[i][ot], 0, 0, 0);
        }
    }

#pragma unroll
    for (int ot = 0; ot < OT; ++ot) {
#pragma unroll
        for (int r = 0; r < 4; ++r) {
            const int o = obq + ot * 16 + agrp * 4 + r;
            const float bs = bias[o] * wscale;
            float4 v;
            v.x = acc[0][ot][r] + bs;
            v.y = acc[1][ot][r] + bs;
            v.z = acc[2][ot][r] + bs;
            v.w = acc[3][ot][r] + bs;
            const long long idx = ((long long)b * storeO + o) * np + p0;
            if (OUTBF == 0) {
                *(float4*)&((float*)outv)[idx] = v;
            } else {
                *(uint2*)&((unsigned short*)outv)[idx] =
                    make_uint2(pack_bf2(v.x, v.y), pack_bf2(v.z, v.w));
            }
        }
    }
}

// ---------------------------------------------------------------------------
// Fused am1+am2 (bf16 I/O), unchanged from r11.
// ---------------------------------------------------------------------------
__global__ __launch_bounds__(256) void k_am_fused(
    const unsigned short* __restrict__ dw,   // bf16: q +0, k +64NP, v +128NP
    const float* __restrict__ w1, const float* __restrict__ b1v,
    const float* __restrict__ w2, const float* __restrict__ b2v,
    unsigned short* __restrict__ hi)         // bf16 hilo ch 0..63
{
    __shared__ __align__(16) uint2 abuf[4][1024];

    const int tid  = threadIdx.x;
    const int lane = tid & 63, wid = tid >> 6;
    const int b    = blockIdx.z;
    const int arow = lane & 15, agrp = lane >> 4;

    bf8 afr1[4][2], afr2[4][2];
#pragma unroll
    for (int ot = 0; ot < 4; ++ot)
#pragma unroll
        for (int kt = 0; kt < 2; ++kt) {
            const float* wp1 = w1 + (long long)(ot * 16 + arow) * 64 + kt * 32 + agrp * 8;
            const float* wp2 = w2 + (long long)(ot * 16 + arow) * 64 + kt * 32 + agrp * 8;
            int4 t1, t2;
            t1.x = (int)pack_bf2(wp1[0], wp1[1]);  t2.x = (int)pack_bf2(wp2[0], wp2[1]);
            t1.y = (int)pack_bf2(wp1[2], wp1[3]);  t2.y = (int)pack_bf2(wp2[2], wp2[3]);
            t1.z = (int)pack_bf2(wp1[4], wp1[5]);  t2.z = (int)pack_bf2(wp2[4], wp2[5]);
            t1.w = (int)pack_bf2(wp1[6], wp1[7]);  t2.w = (int)pack_bf2(wp2[6], wp2[7]);
            afr1[ot][kt] = __builtin_bit_cast(bf8, t1);
            afr2[ot][kt] = __builtin_bit_cast(bf8, t2);
        }

    const unsigned short* xq = dw + (long long)b * (192ll * NP);
    const unsigned short* xk = xq + 64ll * NP;
    const unsigned short* xv = xq + 128ll * NP;

    const int quad = blockIdx.x * 4 + wid;
    const int p0 = quad * 64 + arow * 4;

    f4 acc1[4][4];
#pragma unroll
    for (int i = 0; i < 4; ++i)
#pragma unroll
        for (int ot = 0; ot < 4; ++ot) acc1[i][ot] = (f4){0.f, 0.f, 0.f, 0.f};

#pragma unroll
    for (int kt = 0; kt < 2; ++kt) {
        const long long cbase = kt * 32 + agrp * 8;
        int uu[4][4];
#pragma unroll
        for (int jj = 0; jj < 4; ++jj) {
            ushort4 a0 = *(const ushort4*)&xq[(cbase + 2 * jj) * NP + p0];
            ushort4 a1 = *(const ushort4*)&xq[(cbase + 2 * jj + 1) * NP + p0];
            ushort4 y0 = *(const ushort4*)&xk[(cbase + 2 * jj) * NP + p0];
            ushort4 y1 = *(const ushort4*)&xk[(cbase + 2 * jj + 1) * NP + p0];
            uu[0][jj] = (int)pack_bf2(bf2f(a0.x) * bf2f(y0.x), bf2f(a1.x) * bf2f(y1.x));
            uu[1][jj] = (int)pack_bf2(bf2f(a0.y) * bf2f(y0.y), bf2f(a1.y) * bf2f(y1.y));
            uu[2][jj] = (int)pack_bf2(bf2f(a0.z) * bf2f(y0.z), bf2f(a1.z) * bf2f(y1.z));
            uu[3][jj] = (int)pack_bf2(bf2f(a0.w) * bf2f(y0.w), bf2f(a1.w) * bf2f(y1.w));
        }
#pragma unroll
        for (int i = 0; i < 4; ++i) {
            int4 ti = {uu[i][0], uu[i][1], uu[i][2], uu[i][3]};
            bf8 bfr = __builtin_bit_cast(bf8, ti);
#pragma unroll
            for (int ot = 0; ot < 4; ++ot)
                acc1[i][ot] = __builtin_amdgcn_mfma_f32_16x16x32_bf16(afr1[ot][kt], bfr, acc1[i][ot], 0, 0, 0);
        }
    }

#pragma unroll
    for (int i = 0; i < 4; ++i)
#pragma unroll
        for (int ot = 0; ot < 4; ++ot) {
            const int ch0 = ot * 16 + agrp * 4;
            float v0 = acc1[i][ot][0] + b1v[ch0 + 0];
            float v1 = acc1[i][ot][1] + b1v[ch0 + 1];
            float v2 = acc1[i][ot][2] + b1v[ch0 + 2];
            float v3 = acc1[i][ot][3] + b1v[ch0 + 3];
            v0 = v0 / (1.f + __expf(-v0));
            v1 = v1 / (1.f + __expf(-v1));
            v2 = v2 / (1.f + __expf(-v2));
            v3 = v3 / (1.f + __expf(-v3));
            const int c2 = ot * 4 + agrp;
            abuf[wid][(arow * 4 + i) * 16 + (c2 ^ arow)] =
                make_uint2(pack_bf2(v0, v1), pack_bf2(v2, v3));
        }

    f4 acc2[4][4];
#pragma unroll
    for (int i = 0; i < 4; ++i)
#pragma unroll
        for (int ot = 0; ot < 4; ++ot) acc2[i][ot] = (f4){0.f, 0.f, 0.f, 0.f};

#pragma unroll
    for (int kt = 0; kt < 2; ++kt) {
        const int bc2 = kt * 8 + agrp * 2;
#pragma unroll
        for (int i = 0; i < 4; ++i) {
            const uint2 rA = abuf[wid][(arow * 4 + i) * 16 + (bc2 ^ arow)];
            const uint2 rB = abuf[wid][(arow * 4 + i) * 16 + ((bc2 + 1) ^ arow)];
            int4 ti = make_int4((int)rA.x, (int)rA.y, (int)rB.x, (int)rB.y);
            bf8 bfr = __builtin_bit_cast(bf8, ti);
#pragma unroll
            for (int ot = 0; ot < 4; ++ot)
                acc2[i][ot] = __builtin_amdgcn_mfma_f32_16x16x32_bf16(afr2[ot][kt], bfr, acc2[i][ot], 0, 0, 0);
        }
    }

#pragma unroll
    for (int ot = 0; ot < 4; ++ot) {
#pragma unroll
        for (int r = 0; r < 4; ++r) {
            const int o = ot * 16 + agrp * 4 + r;
            const float bs = b2v[o];
            ushort4 vv4 = *(const ushort4*)&xv[(long long)o * NP + p0];
            float h0 = tanhf((acc2[0][ot][r] + bs) * 0.25f) * bf2f(vv4.x);
            float h1 = tanhf((acc2[1][ot][r] + bs) * 0.25f) * bf2f(vv4.y);
            float h2 = tanhf((acc2[2][ot][r] + bs) * 0.25f) * bf2f(vv4.z);
            float h3 = tanhf((acc2[3][ot][r] + bs) * 0.25f) * bf2f(vv4.w);
            *(uint2*)&hi[((long long)b * 128 + o) * NP + p0] =
                make_uint2(pack_bf2(h0, h1), pack_bf2(h2, h3));
        }
    }
}

// ---------------------------------------------------------------------------
// depthwise 5x5, pad 2 — LDS-staged; bf16 input, bf16 output.
// ---------------------------------------------------------------------------
__global__ __launch_bounds__(256) void k_dwconv5_lds(
    const unsigned short* __restrict__ in, const float* __restrict__ w,
    const float* __restrict__ bias, unsigned short* __restrict__ out, int ch_total)
{
    __shared__ __align__(16) float img[NP];
    const int tid = threadIdx.x;
    const int ch  = blockIdx.x;
    const int b   = blockIdx.y;
    const unsigned short* ip = in + ((long long)b * ch_total + ch) * NP;

#pragma unroll
    for (int j = 0; j < 9; ++j) {
        const uint2 rr = ((const uint2*)ip)[tid + 256 * j];
        float4 f;
        f.x = bflo(rr.x); f.y = bfhi(rr.x);
        f.z = bflo(rr.y); f.w = bfhi(rr.y);
        ((float4*)img)[tid + 256 * j] = f;
    }
    __syncthreads();

    const float* wp = w + ch * 25;
    float wr[25];
#pragma unroll
    for (int i = 0; i < 25; ++i) wr[i] = wp[i];
    const float bs = bias[ch];

    unsigned short* op = out + ((long long)b * ch_total + ch) * NP;

#pragma unroll
    for (int j = 0; j < 9; ++j) {
        const int q  = tid + 256 * j;
        const int y  = q / 24;
        const int x4 = (q - y * 24) * 4;
        float o0 = bs, o1 = bs, o2 = bs, o3 = bs;
#pragma unroll
        for (int ky = 0; ky < 5; ++ky) {
            const int yy = y + ky - 2;
            if (yy < 0 || yy >= HH) continue;
            const float* row = &img[yy * WW + x4];
            float4 mid = *(const float4*)row;
            float4 lf  = (x4 >= 4)      ? *(const float4*)(row - 4)
                                        : make_float4(0.f, 0.f, 0.f, 0.f);
            float4 rt  = (x4 + 4 < WW)  ? *(const float4*)(row + 4)
                                        : make_float4(0.f, 0.f, 0.f, 0.f);
            const float f0 = lf.z,  f1 = lf.w;
            const float f2 = mid.x, f3 = mid.y, f4v = mid.z, f5 = mid.w;
            const float f6 = rt.x,  f7 = rt.y;
            const float w0 = wr[ky * 5 + 0], w1 = wr[ky * 5 + 1],
                        w2 = wr[ky * 5 + 2], w3 = wr[ky * 5 + 3],
                        w4 = wr[ky * 5 + 4];
            o0 = fmaf(w0, f0, o0); o0 = fmaf(w1, f1, o0); o0 = fmaf(w2, f2, o0);
            o0 = fmaf(w3, f3, o0); o0 = fmaf(w4, f4v, o0);
            o1 = fmaf(w0, f1, o1); o1 = fmaf(w1, f2, o1); o1 = fmaf(w2, f3, o1);
            o1 = fmaf(w3, f4v, o1); o1 = fmaf(w4, f5, o1);
            o2 = fmaf(w0, f2, o2); o2 = fmaf(w1, f3, o2); o2 = fmaf(w2, f4v, o2);
            o2 = fmaf(w3, f5, o2); o2 = fmaf(w4, f6, o2);
            o3 = fmaf(w0, f3, o3); o3 = fmaf(w1, f4v, o3); o3 = fmaf(w2, f5, o3);
            o3 = fmaf(w3, f6, o3); o3 = fmaf(w4, f7, o3);
        }
        *(uint2*)&op[y * WW + x4] = make_uint2(pack_bf2(o0, o1), pack_bf2(o2, o3));
    }
}

// ---------------------------------------------------------------------------
// 4x4 average pool  (unchanged, f32)
// ---------------------------------------------------------------------------
__global__ __launch_bounds__(256) void k_avgpool4(
    const float* __restrict__ in, float* __restrict__ out)
{
    int idx = blockIdx.x * 256 + threadIdx.x;
    int total = NB * 128 * NPK;
    if (idx >= total) return;
    int pw = idx % 24;
    int t  = idx / 24;
    int ph = t % 24;  t /= 24;
    int c  = t % 128;
    int b  = t / 128;
    const float* ip = in + ((long long)b * 128 + c) * NP + (ph * 4) * WW + pw * 4;
    float s = 0.f;
#pragma unroll
    for (int i = 0; i < 4; ++i)
#pragma unroll
        for (int j = 0; j < 4; ++j) s += ip[i * WW + j];
    out[idx] = s * (1.0f / 16.0f);
}

// ---------------------------------------------------------------------------
// MFMA flash-attention — unchanged from r11.
// ---------------------------------------------------------------------------
__global__ __launch_bounds__(256) void k_attn_mfma(
    const unsigned short* __restrict__ q,  // bf16 (B,64,NP), pre-scaled by 0.25
    const float* __restrict__ kv,          // f32 (B,128,NPK)
    unsigned short* __restrict__ hilo)     // bf16 (B,128,NP), lo at ch 64..127
{
    __shared__ __align__(16) int4  klds4[36 * 32];
    __shared__ __align__(16) int4  zlds4[32];
    __shared__ __align__(16) int4  vlds4[18 * 64];
    __shared__ __align__(16) uint2 elds2[2][4 * 256];

    const int tid  = threadIdx.x;
    const int lane = tid & 63, wid = tid >> 6;
    const int g    = lane >> 4, qi = lane & 15;
    const int bh   = blockIdx.y, b = bh >> 2, h = bh & 3;

    const float* kbase = kv + ((long long)b * 128 + h * 16) * NPK;
    const float* vbase = kv + ((long long)b * 128 + 64 + h * 16) * NPK;

    for (int i = tid; i < 1152; i += 256) {
        const int key = i >> 1, dg = i & 1;
        const float* kp = kbase + (long long)(dg * 8) * NPK + key;
        int4 t;
        t.x = (int)pack_bf2(kp[0],       kp[NPK]);
        t.y = (int)pack_bf2(kp[2 * NPK], kp[3 * NPK]);
        t.z = (int)pack_bf2(kp[4 * NPK], kp[5 * NPK]);
        t.w = (int)pack_bf2(kp[6 * NPK], kp[7 * NPK]);
        klds4[(key >> 4) * 32 + dg * 16 + (key & 15)] = t;
    }
    for (int i = tid; i < 1152; i += 256) {
        const int t = i >> 6, l = i & 63;
        const float* vp = vbase + (long long)(l & 15) * NPK + t * 32 + (l >> 4) * 8;
        float4 a = *(const float4*)vp;
        float4 c = *(const float4*)(vp + 4);
        int4 tt;
        tt.x = (int)pack_bf2(a.x, a.y);
        tt.y = (int)pack_bf2(a.z, a.w);
        tt.z = (int)pack_bf2(c.x, c.y);
        tt.w = (int)pack_bf2(c.z, c.w);
        vlds4[i] = tt;
    }
    if (tid < 32) zlds4[tid] = make_int4(0, 0, 0, 0);
    __syncthreads();

    const int q0 = (blockIdx.x * 4 + wid) * 32;
    const unsigned short* qcol = q + ((long long)b * 64 + h * 16) * NP + q0 + qi;
    int4 qv[2] = { make_int4(0, 0, 0, 0), make_int4(0, 0, 0, 0) };
    if (g < 2) {
#pragma unroll
        for (int s = 0; s < 2; ++s) {
            const unsigned short* qp = qcol + s * 16 + (long long)(g * 8) * NP;
            qv[s].x = (int)((unsigned)qp[0]          | ((unsigned)qp[(long long)NP]     << 16));
            qv[s].y = (int)((unsigned)qp[2ll * NP]   | ((unsigned)qp[3ll * NP]          << 16));
            qv[s].z = (int)((unsigned)qp[4ll * NP]   | ((unsigned)qp[5ll * NP]          << 16));
            qv[s].w = (int)((unsigned)qp[6ll * NP]   | ((unsigned)qp[7ll * NP]          << 16));
        }
    }

    f4 accp[2] = { (f4){0.f, 0.f, 0.f, 0.f}, (f4){0.f, 0.f, 0.f, 0.f} };
    float den[2] = { 0.f, 0.f };

    auto QKEXP = [&](int k2, int buf) {
#pragma unroll
        for (int tp = 0; tp < 2; ++tp) {
            const int4 kf = (lane < 32) ? klds4[(k2 * 2 + tp) * 32 + lane]
                                        : zlds4[lane & 31];
            const bf8 ka = __builtin_bit_cast(bf8, kf);
#pragma unroll
            for (int s = 0; s < 2; ++s) {
                f4 sa = __builtin_amdgcn_mfma_f32_16x16x32_bf16(
                    ka, __builtin_bit_cast(bf8, qv[s]), (f4){0.f, 0.f, 0.f, 0.f}, 0, 0, 0);
                const float e0 = __expf(sa[0]), e1 = __expf(sa[1]);
                const float e2 = __expf(sa[2]), e3 = __expf(sa[3]);
                den[s] += (e0 + e1) + (e2 + e3);
                elds2[buf][wid * 256 + s * 128 + tp * 64 + g * 16 + qi] =
                    make_uint2(pack_bf2(e0, e1), pack_bf2(e2, e3));
            }
        }
    };
    auto PV = [&](int k2, int buf) {
        const bf8 va = __builtin_bit_cast(bf8, vlds4[k2 * 64 + lane]);
#pragma unroll
        for (int s = 0; s < 2; ++s) {
            const int base = wid * 256 + s * 128 + (g >> 1) * 64 + (g & 1) * 32 + qi;
            const uint2 r0 = elds2[buf][base];
            const uint2 r1 = elds2[buf][base + 16];
            int4 ti = make_int4((int)r0.x, (int)r0.y, (int)r1.x, (int)r1.y);
            accp[s] = __builtin_amdgcn_mfma_f32_16x16x32_bf16(
                va, __builtin_bit_cast(bf8, ti), accp[s], 0, 0, 0);
        }
    };

    QKEXP(0, 0);
    for (int k2 = 0; k2 < 17; ++k2) {
        QKEXP(k2 + 1, (k2 + 1) & 1);
        PV(k2, k2 & 1);
    }
    PV(17, 1);

#pragma unroll
    for (int s = 0; s < 2; ++s) {
        float d0 = den[s];
        d0 += __shfl_xor(d0, 16, 64);
        d0 += __shfl_xor(d0, 32, 64);
        const float inv = 1.0f / d0;
        unsigned short* op = hilo + ((long long)b * 128 + 64 + h * 16 + g * 4) * NP + q0 + s * 16 + qi;
#pragma unroll
        for (int r = 0; r < 4; ++r)
            op[(long long)r * NP] = f2bfu(accp[s][r] * inv);
    }
}

// ---------------------------------------------------------------------------
extern "C" void kernel_launch(void* const* d_in, const int* in_sizes, int n_in,
                              void* d_out, int out_size, void* d_ws, size_t ws_size,
                              hipStream_t stream)
{
    const float* x      = (const float*)d_in[0];
    const float* qkv_w  = (const float*)d_in[1];
    const float* qkv_b  = (const float*)d_in[2];
    const float* dw_w   = (const float*)d_in[3];
    const float* dw_b   = (const float*)d_in[4];
    const float* am_w1  = (const float*)d_in[5];
    const float* am_b1  = (const float*)d_in[6];
    const float* am_w2  = (const float*)d_in[7];
    const float* am_b2  = (const float*)d_in[8];
    const float* gq_w   = (const float*)d_in[9];
    const float* gq_b   = (const float*)d_in[10];
    const float* gkv_w  = (const float*)d_in[11];
    const float* gkv_b  = (const float*)d_in[12];
    const float* proj_w = (const float*)d_in[13];
    const float* proj_b = (const float*)d_in[14];
    float* out = (float*)d_out;
    char* wsb = (char*)d_ws;

    // byte layout; t_qkv region dead after dwconv, reused by t_hilo
    unsigned short* t_qkv  = (unsigned short*)wsb;               // bf16 (8,192,9216) 28.3MB
    unsigned short* t_hilo = (unsigned short*)wsb;               // bf16 (8,128,9216) 18.9MB (reuse)
    unsigned short* t_dw   = (unsigned short*)(wsb + 28311552);  // bf16 (8,192,9216) 28.3MB
    unsigned short* t_gq   = (unsigned short*)(wsb + 56623104);  // bf16 (8,64,9216)   9.4MB
    float*          t_pool = (float*)(wsb + 66060288);           // f32 (8,128,576)
    float*          t_gkv  = (float*)(wsb + 68419584);           // f32 (8,128,576)

    // 1. qkv (bf16) + gq (bf16, *0.25) from one LDS-staged read of x
    k_qkvgq<<<dim3(144, 1, NB), 256, 0, stream>>>(
        x, qkv_w, qkv_b, gq_w, gq_b, t_qkv, t_gq);
    // 2. depthwise 5x5 (bf16 in -> bf16 out)
    k_dwconv5_lds<<<dim3(192, NB), 256, 0, stream>>>(t_qkv, dw_w, dw_b, t_dw, 192);
    // 3. pooled = avgpool4(x)
    k_avgpool4<<<dim3((NB*128*NPK + 255)/256), 256, 0, stream>>>(x, t_pool);
    // 4. gkv = conv1x1(pooled)  f32 out
    k_mfma_conv<128,4,0,0><<<dim3(3,2,NB), 256, 0, stream>>>(
        t_pool, gkv_w, gkv_b, t_gkv, NPK, (long long)128 * NPK, 128, 1.0f);
    // 5. fused am -> hilo ch 0..63 (bf16)
    k_am_fused<<<dim3(36,1,NB), 256, 0, stream>>>(
        t_dw, am_w1, am_b1, am_w2, am_b2, t_hilo);
    // 6. attention -> hilo ch 64..127 (bf16)
    k_attn_mfma<<<dim3(72, 32), 256, 0, stream>>>(t_gq, t_gkv, t_hilo);
    // 7. out = conv1x1(hilo bf16, proj_w)  f32 out
    k_mfma_conv<128,4,1,0><<<dim3(36,2,NB), 256, 0, stream>>>(
        t_hilo, proj_w, proj_b, out, NP, (long long)128 * NP, 128, 1.0f);
}